// Round 1
// baseline (1513.269 us; speedup 1.0000x reference)
//
#include <hip/hip_runtime.h>
#include <hip/hip_fp16.h>

#define NTOK 1024
#define INF  1024
#define NH   16
#define DH   64
#define BDIM 512
#define NMEM 8192
#define OUTF 1024
#define NWRD 16   // 512 bits = 16 u32

typedef _Float16 f16x8 __attribute__((ext_vector_type(8)));
typedef float    f32x4 __attribute__((ext_vector_type(4)));

// ---------------- K1: q = x @ Wq^T + bq (f32, 64x64 tile) ----------------
__global__ __launch_bounds__(256) void k_qgemm(const float* __restrict__ x,
    const float* __restrict__ Wq, const float* __restrict__ bq, float* __restrict__ q) {
  __shared__ float As[64][17];
  __shared__ float Bs[64][17];
  const int tx = threadIdx.x & 15, ty = threadIdx.x >> 4;
  const int n0 = blockIdx.y * 64, o0 = blockIdx.x * 64;
  const int r = threadIdx.x >> 2, c4 = (threadIdx.x & 3) * 4;
  float acc[4][4] = {};
  for (int k0 = 0; k0 < INF; k0 += 16) {
    float4 av = *(const float4*)&x[(size_t)(n0 + r) * INF + k0 + c4];
    float4 bv = *(const float4*)&Wq[(size_t)(o0 + r) * INF + k0 + c4];
    __syncthreads();               // prev compute done before LDS overwrite
    As[r][c4+0] = av.x; As[r][c4+1] = av.y; As[r][c4+2] = av.z; As[r][c4+3] = av.w;
    Bs[r][c4+0] = bv.x; Bs[r][c4+1] = bv.y; Bs[r][c4+2] = bv.z; Bs[r][c4+3] = bv.w;
    __syncthreads();
    #pragma unroll
    for (int kk = 0; kk < 16; ++kk) {
      float a[4], b[4];
      #pragma unroll
      for (int i = 0; i < 4; ++i) a[i] = As[ty*4+i][kk];
      #pragma unroll
      for (int j = 0; j < 4; ++j) b[j] = Bs[tx*4+j][kk];
      #pragma unroll
      for (int i = 0; i < 4; ++i)
        #pragma unroll
        for (int j = 0; j < 4; ++j) acc[i][j] += a[i] * b[j];
    }
  }
  #pragma unroll
  for (int i = 0; i < 4; ++i) {
    const int row = n0 + ty*4 + i;
    #pragma unroll
    for (int j = 0; j < 4; ++j) {
      const int col = o0 + tx*4 + j;
      q[(size_t)row * OUTF + col] = acc[i][j] + bq[col];
    }
  }
}

// ---------------- K2: code = sign(q . bin_proj), bit-packed ----------------
// norm of q doesn't change sign -> skip normalization entirely
__global__ __launch_bounds__(256) void k_code(const float* __restrict__ q,
    const float* __restrict__ bp, unsigned* __restrict__ code) {
  const int h = blockIdx.y, n0 = blockIdx.x * 16;
  __shared__ float ql[16][68];
  const int t = threadIdx.x;
  {
    const int r = t >> 4, c = (t & 15) * 4;
    float4 v = *(const float4*)&q[(size_t)(n0 + r) * OUTF + h * 64 + c];
    ql[r][c] = v.x; ql[r][c+1] = v.y; ql[r][c+2] = v.z; ql[r][c+3] = v.w;
  }
  __syncthreads();
  const int lane = t & 63, wv = t >> 6;
  #pragma unroll
  for (int bb = 0; bb < 512; bb += 256) {
    const int b = bb + t;
    float bpv[64];
    const float4* src = (const float4*)&bp[((size_t)h * BDIM + b) * 64];
    #pragma unroll
    for (int j = 0; j < 16; ++j) {
      float4 v = src[j];
      bpv[j*4] = v.x; bpv[j*4+1] = v.y; bpv[j*4+2] = v.z; bpv[j*4+3] = v.w;
    }
    const int w0 = (bb + wv * 64) >> 5;
    for (int n = 0; n < 16; ++n) {
      float dot = 0.f;
      #pragma unroll
      for (int d = 0; d < 64; ++d) dot += bpv[d] * ql[n][d];
      unsigned long long msk = __ballot(dot > 0.f);
      if (lane == 0) {
        code[(size_t)(h * NTOK + n0 + n) * NWRD + w0]     = (unsigned)msk;
        code[(size_t)(h * NTOK + n0 + n) * NWRD + w0 + 1] = (unsigned)(msk >> 32);
      }
    }
  }
}

// ---------------- K3: pack weight_matrix signs into bits (wave per row) ----
__global__ __launch_bounds__(256) void k_packw(const float* __restrict__ w,
                                               unsigned* __restrict__ wp) {
  const int row  = blockIdx.x * 4 + (threadIdx.x >> 6);
  const int lane = threadIdx.x & 63;
  const float* src = w + (size_t)row * BDIM;
  unsigned my = 0;
  #pragma unroll
  for (int kk = 0; kk < 8; ++kk) {
    float v = src[kk * 64 + lane];
    unsigned long long m = __ballot(v > 0.f);
    if ((lane >> 1) == kk) my = (lane & 1) ? (unsigned)(m >> 32) : (unsigned)m;
  }
  if (lane < 16) wp[(size_t)row * NWRD + lane] = my;
}

// ---------------- K3b: transpose bin_inv [h][d][b] -> binT [h][b][d] -------
__global__ __launch_bounds__(256) void k_binT(const float* __restrict__ binv,
                                              float* __restrict__ bT) {
  const int h = blockIdx.y, b0 = blockIdx.x * 64;
  __shared__ float tl[64][65];
  const int t = threadIdx.x;
  #pragma unroll
  for (int i = 0; i < 4; ++i) {
    int fi = t + 256 * i;
    int d = fi >> 4, b = (fi & 15) * 4;
    float4 v = *(const float4*)&binv[((size_t)h * DH + d) * BDIM + b0 + b];
    tl[d][b] = v.x; tl[d][b+1] = v.y; tl[d][b+2] = v.z; tl[d][b+3] = v.w;
  }
  __syncthreads();
  #pragma unroll
  for (int i = 0; i < 4; ++i) {
    int fo = t + 256 * i;
    int bb = fo >> 4, dd = (fo & 15) * 4;
    float4 v = { tl[dd][bb], tl[dd+1][bb], tl[dd+2][bb], tl[dd+3][bb] };
    *(float4*)&bT[((size_t)h * BDIM + b0 + bb) * DH + dd] = v;
  }
}

// ---------------- K4: expand bits -> f16 w_t [hg][b][m] (+-1) --------------
__global__ __launch_bounds__(256) void k_wt(const unsigned* __restrict__ wp,
    unsigned short* __restrict__ wt, int h0) {
  const int hg = blockIdx.z, h = h0 + hg;
  const int b0 = blockIdx.y * 64, m0 = blockIdx.x * 256;
  __shared__ unsigned bits[256][2];
  const int t = threadIdx.x;
  const unsigned* src = wp + (size_t)(h * NMEM + m0 + t) * NWRD + (b0 >> 5);
  bits[t][0] = src[0]; bits[t][1] = src[1];
  __syncthreads();
  const int b = t >> 2, ms = (t & 3) * 64;
  const int wd = b >> 5, sh = b & 31;
  unsigned short* dst = wt + ((size_t)hg * BDIM + b0 + b) * NMEM + m0 + ms;
  #pragma unroll
  for (int j = 0; j < 64; j += 4) {
    ushort4 v;
    v.x = ((bits[ms+j+0][wd] >> sh) & 1) ? 0x3C00 : 0xBC00;
    v.y = ((bits[ms+j+1][wd] >> sh) & 1) ? 0x3C00 : 0xBC00;
    v.z = ((bits[ms+j+2][wd] >> sh) & 1) ? 0x3C00 : 0xBC00;
    v.w = ((bits[ms+j+3][wd] >> sh) & 1) ? 0x3C00 : 0xBC00;
    *(ushort4*)&dst[j] = v;
  }
}

// ------- K5: fused sim (xor+popcount, exact) + softmax -> attn f16 ---------
// block = (head, 8 query rows), 512 threads; sims live in registers (2/u32)
__global__ __launch_bounds__(512) void k_simsm(const unsigned* __restrict__ code,
    const unsigned* __restrict__ wp, unsigned short* __restrict__ attn, int h0) {
  const int hg = blockIdx.y, h = h0 + hg;
  const int n0 = blockIdx.x * 8;
  const int t = threadIdx.x;
  __shared__ unsigned cl[8][16];
  __shared__ float score_t[513];
  __shared__ float redf[8][8];
  __shared__ int   redi[8][8];
  if (t < 128) cl[t >> 4][t & 15] =
      code[(size_t)(h * NTOK + n0 + (t >> 4)) * NWRD + (t & 15)];
  for (int p = t; p < 513; p += 512) {
    float sim = (512.f - 2.f * (float)p) * (1.f / 512.f);
    score_t[p] = cosf(1.57079632679489662f * (1.f - sim));   // same formula as ref
  }
  __syncthreads();
  unsigned pops[8][8];
  const uint4* wv4 = (const uint4*)(wp + (size_t)h * NMEM * NWRD);
  #pragma unroll
  for (int k = 0; k < 16; ++k) {
    const int m = (k << 9) + t;
    uint4 w0 = wv4[(size_t)m*4+0], w1 = wv4[(size_t)m*4+1];
    uint4 w2 = wv4[(size_t)m*4+2], w3 = wv4[(size_t)m*4+3];
    #pragma unroll
    for (int r = 0; r < 8; ++r) {
      const uint4* c4 = (const uint4*)cl[r];
      uint4 c0 = c4[0], c1 = c4[1], c2 = c4[2], c3 = c4[3];
      int pop = __popc(c0.x^w0.x) + __popc(c0.y^w0.y) + __popc(c0.z^w0.z) + __popc(c0.w^w0.w)
              + __popc(c1.x^w1.x) + __popc(c1.y^w1.y) + __popc(c1.z^w1.z) + __popc(c1.w^w1.w)
              + __popc(c2.x^w2.x) + __popc(c2.y^w2.y) + __popc(c2.z^w2.z) + __popc(c2.w^w2.w)
              + __popc(c3.x^w3.x) + __popc(c3.y^w3.y) + __popc(c3.z^w3.z) + __popc(c3.w^w3.w);
      if (k & 1) pops[r][k >> 1] |= (unsigned)pop << 16;
      else       pops[r][k >> 1]  = (unsigned)pop;
    }
  }
  const int lane = t & 63, wid = t >> 6;
  #pragma unroll
  for (int r = 0; r < 8; ++r) {          // min pop == max score
    int mn = 1 << 30;
    #pragma unroll
    for (int kk = 0; kk < 8; ++kk) {
      mn = min(mn, (int)(pops[r][kk] & 0xffffu));
      mn = min(mn, (int)(pops[r][kk] >> 16));
    }
    #pragma unroll
    for (int off = 32; off; off >>= 1) mn = min(mn, __shfl_down(mn, off));
    if (lane == 0) redi[r][wid] = mn;
  }
  __syncthreads();
  float smax[8];
  #pragma unroll
  for (int r = 0; r < 8; ++r) {
    int mn = redi[r][0];
    #pragma unroll
    for (int wv = 1; wv < 8; ++wv) mn = min(mn, redi[r][wv]);
    smax[r] = score_t[mn];
  }
  #pragma unroll
  for (int r = 0; r < 8; ++r) {          // exp + Z; repack p as f16 bits
    float z = 0.f;
    #pragma unroll
    for (int k = 0; k < 16; ++k) {
      unsigned pv = pops[r][k >> 1];
      int pop = (k & 1) ? (int)(pv >> 16) : (int)(pv & 0xffffu);
      float pr = __expf((score_t[pop] - smax[r]) * 100.f);   // /TEMP
      z += pr;
      unsigned hb = (unsigned)__half_as_ushort(__float2half(pr));
      if (k & 1) pops[r][k >> 1] = (pv & 0x0000ffffu) | (hb << 16);
      else       pops[r][k >> 1] = (pv & 0xffff0000u) | hb;
    }
    #pragma unroll
    for (int off = 32; off; off >>= 1) z += __shfl_down(z, off);
    if (lane == 0) redf[r][wid] = z;
  }
  __syncthreads();
  float zinv[8];
  #pragma unroll
  for (int r = 0; r < 8; ++r) {
    float z = redf[r][0];
    #pragma unroll
    for (int wv = 1; wv < 8; ++wv) z += redf[r][wv];
    zinv[r] = 1.f / z;
  }
  #pragma unroll
  for (int k = 0; k < 16; ++k) {
    const int m = (k << 9) + t;
    #pragma unroll
    for (int r = 0; r < 8; ++r) {
      unsigned pv = pops[r][k >> 1];
      float pr = __half2float(__ushort_as_half(
          (unsigned short)((k & 1) ? (pv >> 16) : (pv & 0xffffu))));
      attn[((size_t)hg * NTOK + n0 + r) * NMEM + m] =
          __half_as_ushort(__float2half(pr * zinv[r]));
    }
  }
}

// ------- K6: o1^T[hg][b][n] = (attn @ w)^T via f16 MFMA, 128x256 tile ------
__global__ __launch_bounds__(512) void k_stageF(const unsigned short* __restrict__ attn,
    const unsigned short* __restrict__ wt, float* __restrict__ o1t) {
  __shared__ _Float16 Al[128][72];
  __shared__ _Float16 Bl[256][72];
  const int nwg = (int)gridDim.x;       // G*16, always %8==0 -> bijective swizzle
  const int cpx = nwg >> 3;
  const int wg  = (int)blockIdx.x;
  const int swz = (wg & 7) * cpx + (wg >> 3);
  const int hg = swz >> 4, bt = (swz >> 3) & 1, nt = swz & 7;
  const int n0 = nt * 128, b0 = bt * 256;
  const int t = threadIdx.x;
  const int lane = t & 63, wid = t >> 6;
  const int wm = wid >> 2, wn = wid & 3;
  f32x4 acc[4][4];
  #pragma unroll
  for (int i = 0; i < 4; ++i)
    #pragma unroll
    for (int j = 0; j < 4; ++j) acc[i][j] = (f32x4){0.f, 0.f, 0.f, 0.f};

  const int ar = t >> 2, as = (t & 3) * 16;
  const int br = t >> 1, bs = (t & 1) * 32;
  const unsigned short* asrc = attn + ((size_t)hg * NTOK + n0 + ar) * NMEM + as;
  const unsigned short* bsrc = wt   + ((size_t)hg * BDIM + b0 + br) * NMEM + bs;

  for (int k0 = 0; k0 < NMEM; k0 += 64) {
    uint4 a0  = *(const uint4*)(asrc + k0);
    uint4 a1  = *(const uint4*)(asrc + k0 + 8);
    uint4 bv0 = *(const uint4*)(bsrc + k0);
    uint4 bv1 = *(const uint4*)(bsrc + k0 + 8);
    uint4 bv2 = *(const uint4*)(bsrc + k0 + 16);
    uint4 bv3 = *(const uint4*)(bsrc + k0 + 24);
    __syncthreads();
    *(uint4*)&Al[ar][as]      = a0;
    *(uint4*)&Al[ar][as + 8]  = a1;
    *(uint4*)&Bl[br][bs]      = bv0;
    *(uint4*)&Bl[br][bs + 8]  = bv1;
    *(uint4*)&Bl[br][bs + 16] = bv2;
    *(uint4*)&Bl[br][bs + 24] = bv3;
    __syncthreads();
    #pragma unroll
    for (int kk = 0; kk < 64; kk += 32) {
      f16x8 af[4], bf[4];
      #pragma unroll
      for (int fm = 0; fm < 4; ++fm)
        af[fm] = *(const f16x8*)&Al[wm*64 + fm*16 + (lane & 15)][kk + (lane >> 4) * 8];
      #pragma unroll
      for (int fn = 0; fn < 4; ++fn)
        bf[fn] = *(const f16x8*)&Bl[wn*64 + fn*16 + (lane & 15)][kk + (lane >> 4) * 8];
      #pragma unroll
      for (int fm = 0; fm < 4; ++fm)
        #pragma unroll
        for (int fn = 0; fn < 4; ++fn)
          acc[fm][fn] = __builtin_amdgcn_mfma_f32_16x16x32_f16(af[fm], bf[fn], acc[fm][fn], 0, 0, 0);
    }
  }
  #pragma unroll
  for (int fm = 0; fm < 4; ++fm) {
    const int rowb = n0 + wm*64 + fm*16 + (lane >> 4) * 4;   // C: row=(l>>4)*4+reg
    #pragma unroll
    for (int fn = 0; fn < 4; ++fn) {
      const int col = b0 + wn*64 + fn*16 + (lane & 15);      // C: col=l&15
      *(f32x4*)&o1t[((size_t)hg * BDIM + col) * NTOK + rowb] = acc[fm][fn];
    }
  }
}

// ------- K7: out[n][h*64+d] = normalize_d( o1 . bin_inv ) ------------------
__global__ __launch_bounds__(256) void k_proj(const float* __restrict__ o1t,
    const float* __restrict__ bT, float* __restrict__ o2, int h0) {
  const int hg = blockIdx.y, h = h0 + hg;
  const int n0 = blockIdx.x * 64;
  __shared__ float bl[128][68];
  __shared__ float ol[128][68];
  __shared__ float outl[64][68];
  __shared__ float nrm[64];
  const int t = threadIdx.x;
  const int tx = t & 15, ty = t >> 4;
  float acc[4][4] = {};
  for (int c = 0; c < 4; ++c) {
    const int bb0 = c * 128;
    __syncthreads();
    #pragma unroll
    for (int i = 0; i < 8; ++i) {
      int fi = t + 256 * i;
      int rr = fi >> 4, cc = (fi & 15) * 4;
      *(float4*)&bl[rr][cc] = *(const float4*)&bT[((size_t)h * BDIM + bb0 + rr) * DH + cc];
      *(float4*)&ol[rr][cc] = *(const float4*)&o1t[((size_t)hg * BDIM + bb0 + rr) * NTOK + n0 + cc];
    }
    __syncthreads();
    for (int bb = 0; bb < 128; ++bb) {
      float4 bd = *(const float4*)&bl[bb][tx * 4];
      float4 on = *(const float4*)&ol[bb][ty * 4];
      float ai[4] = {on.x, on.y, on.z, on.w};
      float bj[4] = {bd.x, bd.y, bd.z, bd.w};
      #pragma unroll
      for (int i = 0; i < 4; ++i)
        #pragma unroll
        for (int j = 0; j < 4; ++j) acc[i][j] += ai[i] * bj[j];
    }
  }
  __syncthreads();
  #pragma unroll
  for (int i = 0; i < 4; ++i)
    #pragma unroll
    for (int j = 0; j < 4; ++j) outl[ty*4 + i][tx*4 + j] = acc[i][j];
  __syncthreads();
  if (t < 64) {
    float s = 0.f;
    #pragma unroll
    for (int d = 0; d < 64; ++d) { float v = outl[t][d]; s += v * v; }
    nrm[t] = 1.f / sqrtf(s);
  }
  __syncthreads();
  {
    const int n = t >> 2, dg = (t & 3) * 16;
    #pragma unroll
    for (int j = 0; j < 16; ++j)
      o2[(size_t)(n0 + n) * OUTF + h * 64 + dg + j] = outl[n][dg + j] * nrm[n];
  }
}

// ------- K8: LayerNorm over 1024 features ----------------------------------
__global__ __launch_bounds__(256) void k_ln(const float* __restrict__ o2,
    const float* __restrict__ lnw, const float* __restrict__ lnb, float* __restrict__ out) {
  const int n = blockIdx.x, t = threadIdx.x;
  __shared__ float red[4];
  float4 v = *(const float4*)&o2[(size_t)n * OUTF + t * 4];
  float s = v.x + v.y + v.z + v.w;
  const int lane = t & 63, wid = t >> 6;
  #pragma unroll
  for (int off = 32; off; off >>= 1) s += __shfl_down(s, off);
  if (lane == 0) red[wid] = s;
  __syncthreads();
  const float mu = (red[0] + red[1] + red[2] + red[3]) * (1.f / 1024.f);
  float4 d = {v.x - mu, v.y - mu, v.z - mu, v.w - mu};
  float s2 = d.x*d.x + d.y*d.y + d.z*d.z + d.w*d.w;
  #pragma unroll
  for (int off = 32; off; off >>= 1) s2 += __shfl_down(s2, off);
  __syncthreads();
  if (lane == 0) red[wid] = s2;
  __syncthreads();
  const float var = (red[0] + red[1] + red[2] + red[3]) * (1.f / 1024.f);
  const float inv = 1.f / sqrtf(var + 1e-5f);
  float4 w = *(const float4*)&lnw[t * 4];
  float4 b = *(const float4*)&lnb[t * 4];
  float4 o = { d.x*inv*w.x + b.x, d.y*inv*w.y + b.y,
               d.z*inv*w.z + b.z, d.w*inv*w.w + b.w };
  *(float4*)&out[(size_t)n * OUTF + t * 4] = o;
}

extern "C" void kernel_launch(void* const* d_in, const int* in_sizes, int n_in,
                              void* d_out, int out_size, void* d_ws, size_t ws_size,
                              hipStream_t stream) {
  (void)in_sizes; (void)n_in; (void)out_size;
  const float* x    = (const float*)d_in[0];
  const float* Wq   = (const float*)d_in[1];
  const float* bq   = (const float*)d_in[2];
  const float* bp   = (const float*)d_in[3];
  const float* binv = (const float*)d_in[4];
  const float* wm   = (const float*)d_in[5];
  const float* lnw  = (const float*)d_in[6];
  const float* lnb  = (const float*)d_in[7];
  float* outp = (float*)d_out;

  char* ws = (char*)d_ws;
  size_t off = 0;
  auto carve = [&](size_t bytes) -> char* {
    char* p = ws + off;
    off += (bytes + 255) & ~(size_t)255;
    return p;
  };
  float*    q    = (float*)   carve((size_t)NTOK * OUTF * 4);
  unsigned* code = (unsigned*)carve((size_t)NH * NTOK * NWRD * 4);
  unsigned* wpk  = (unsigned*)carve((size_t)NH * NMEM * NWRD * 4);
  float*    bT   = (float*)   carve((size_t)NH * BDIM * DH * 4);
  float*    o2   = (float*)   carve((size_t)NTOK * OUTF * 4);
  const size_t fixed = off;
  const size_t per = ((size_t)BDIM * NMEM * 2 + 256)
                   + ((size_t)NTOK * NMEM * 2 + 256)
                   + ((size_t)BDIM * NTOK * 4 + 256);
  int G = 16;
  while (G > 1 && fixed + (size_t)G * per > ws_size) G >>= 1;
  unsigned short* wt   = (unsigned short*)carve((size_t)G * BDIM * NMEM * 2);
  unsigned short* attn = (unsigned short*)carve((size_t)G * NTOK * NMEM * 2);
  float*          o1t  = (float*)         carve((size_t)G * BDIM * NTOK * 4);

  k_qgemm<<<dim3(16, 16), 256, 0, stream>>>(x, Wq, bq, q);
  k_code <<<dim3(64, 16), 256, 0, stream>>>(q, bp, code);
  k_packw<<<dim3(NH * NMEM / 4), 256, 0, stream>>>(wm, wpk);
  k_binT <<<dim3(8, 16), 256, 0, stream>>>(binv, bT);
  for (int h0 = 0; h0 < NH; h0 += G) {
    k_wt    <<<dim3(32, 8, G), 256, 0, stream>>>(wpk, wt, h0);
    k_simsm <<<dim3(128, G),   512, 0, stream>>>(code, wpk, attn, h0);
    k_stageF<<<dim3(G * 16),   512, 0, stream>>>(attn, wt, o1t);
    k_proj  <<<dim3(16, G),    256, 0, stream>>>(o1t, bT, o2, h0);
  }
  k_ln<<<dim3(NTOK), 256, 0, stream>>>(o2, lnw, lnb, outp);
}

// Round 2
// 1389.634 us; speedup vs baseline: 1.0890x; 1.0890x over previous
//
#include <hip/hip_runtime.h>
#include <hip/hip_fp16.h>

#define NTOK 1024
#define INF  1024
#define NH   16
#define DH   64
#define BDIM 512
#define NMEM 8192
#define OUTF 1024
#define NWRD 16   // 512 bits = 16 u32

typedef _Float16 f16x8 __attribute__((ext_vector_type(8)));
typedef float    f32x4 __attribute__((ext_vector_type(4)));

// ---------------- K1: q = x @ Wq^T + bq (f32, 64x64 tile) ----------------
__global__ __launch_bounds__(256) void k_qgemm(const float* __restrict__ x,
    const float* __restrict__ Wq, const float* __restrict__ bq, float* __restrict__ q) {
  __shared__ float As[64][17];
  __shared__ float Bs[64][17];
  const int tx = threadIdx.x & 15, ty = threadIdx.x >> 4;
  const int n0 = blockIdx.y * 64, o0 = blockIdx.x * 64;
  const int r = threadIdx.x >> 2, c4 = (threadIdx.x & 3) * 4;
  float acc[4][4] = {};
  for (int k0 = 0; k0 < INF; k0 += 16) {
    float4 av = *(const float4*)&x[(size_t)(n0 + r) * INF + k0 + c4];
    float4 bv = *(const float4*)&Wq[(size_t)(o0 + r) * INF + k0 + c4];
    __syncthreads();               // prev compute done before LDS overwrite
    As[r][c4+0] = av.x; As[r][c4+1] = av.y; As[r][c4+2] = av.z; As[r][c4+3] = av.w;
    Bs[r][c4+0] = bv.x; Bs[r][c4+1] = bv.y; Bs[r][c4+2] = bv.z; Bs[r][c4+3] = bv.w;
    __syncthreads();
    #pragma unroll
    for (int kk = 0; kk < 16; ++kk) {
      float a[4], b[4];
      #pragma unroll
      for (int i = 0; i < 4; ++i) a[i] = As[ty*4+i][kk];
      #pragma unroll
      for (int j = 0; j < 4; ++j) b[j] = Bs[tx*4+j][kk];
      #pragma unroll
      for (int i = 0; i < 4; ++i)
        #pragma unroll
        for (int j = 0; j < 4; ++j) acc[i][j] += a[i] * b[j];
    }
  }
  #pragma unroll
  for (int i = 0; i < 4; ++i) {
    const int row = n0 + ty*4 + i;
    #pragma unroll
    for (int j = 0; j < 4; ++j) {
      const int col = o0 + tx*4 + j;
      q[(size_t)row * OUTF + col] = acc[i][j] + bq[col];
    }
  }
}

// ---------------- K2: code = sign(q . bin_proj), bit-packed ----------------
// norm of q doesn't change sign -> skip normalization entirely
__global__ __launch_bounds__(256) void k_code(const float* __restrict__ q,
    const float* __restrict__ bp, unsigned* __restrict__ code) {
  const int h = blockIdx.y, n0 = blockIdx.x * 16;
  __shared__ float ql[16][68];
  const int t = threadIdx.x;
  {
    const int r = t >> 4, c = (t & 15) * 4;
    float4 v = *(const float4*)&q[(size_t)(n0 + r) * OUTF + h * 64 + c];
    ql[r][c] = v.x; ql[r][c+1] = v.y; ql[r][c+2] = v.z; ql[r][c+3] = v.w;
  }
  __syncthreads();
  const int lane = t & 63, wv = t >> 6;
  #pragma unroll
  for (int bb = 0; bb < 512; bb += 256) {
    const int b = bb + t;
    float bpv[64];
    const float4* src = (const float4*)&bp[((size_t)h * BDIM + b) * 64];
    #pragma unroll
    for (int j = 0; j < 16; ++j) {
      float4 v = src[j];
      bpv[j*4] = v.x; bpv[j*4+1] = v.y; bpv[j*4+2] = v.z; bpv[j*4+3] = v.w;
    }
    const int w0 = (bb + wv * 64) >> 5;
    for (int n = 0; n < 16; ++n) {
      float dot = 0.f;
      #pragma unroll
      for (int d = 0; d < 64; ++d) dot += bpv[d] * ql[n][d];
      unsigned long long msk = __ballot(dot > 0.f);
      if (lane == 0) {
        code[(size_t)(h * NTOK + n0 + n) * NWRD + w0]     = (unsigned)msk;
        code[(size_t)(h * NTOK + n0 + n) * NWRD + w0 + 1] = (unsigned)(msk >> 32);
      }
    }
  }
}

// ---------------- K3: pack weight_matrix signs into bits (wave per row) ----
__global__ __launch_bounds__(256) void k_packw(const float* __restrict__ w,
                                               unsigned* __restrict__ wp) {
  const int row  = blockIdx.x * 4 + (threadIdx.x >> 6);
  const int lane = threadIdx.x & 63;
  const float* src = w + (size_t)row * BDIM;
  unsigned my = 0;
  #pragma unroll
  for (int kk = 0; kk < 8; ++kk) {
    float v = src[kk * 64 + lane];
    unsigned long long m = __ballot(v > 0.f);
    if ((lane >> 1) == kk) my = (lane & 1) ? (unsigned)(m >> 32) : (unsigned)m;
  }
  if (lane < 16) wp[(size_t)row * NWRD + lane] = my;
}

// ---------------- K3b: transpose bin_inv [h][d][b] -> binT [h][b][d] -------
__global__ __launch_bounds__(256) void k_binT(const float* __restrict__ binv,
                                              float* __restrict__ bT) {
  const int h = blockIdx.y, b0 = blockIdx.x * 64;
  __shared__ float tl[64][65];
  const int t = threadIdx.x;
  #pragma unroll
  for (int i = 0; i < 4; ++i) {
    int fi = t + 256 * i;
    int d = fi >> 4, b = (fi & 15) * 4;
    float4 v = *(const float4*)&binv[((size_t)h * DH + d) * BDIM + b0 + b];
    tl[d][b] = v.x; tl[d][b+1] = v.y; tl[d][b+2] = v.z; tl[d][b+3] = v.w;
  }
  __syncthreads();
  #pragma unroll
  for (int i = 0; i < 4; ++i) {
    int fo = t + 256 * i;
    int bb = fo >> 4, dd = (fo & 15) * 4;
    float4 v = { tl[dd][bb], tl[dd+1][bb], tl[dd+2][bb], tl[dd+3][bb] };
    *(float4*)&bT[((size_t)h * BDIM + b0 + bb) * DH + dd] = v;
  }
}

// ---------------- K4: expand bits -> f16 w_t [hg][b][m] (+-1) --------------
__global__ __launch_bounds__(256) void k_wt(const unsigned* __restrict__ wp,
    unsigned short* __restrict__ wt, int h0) {
  const int hg = blockIdx.z, h = h0 + hg;
  const int b0 = blockIdx.y * 64, m0 = blockIdx.x * 256;
  __shared__ unsigned bits[256][2];
  const int t = threadIdx.x;
  const unsigned* src = wp + (size_t)(h * NMEM + m0 + t) * NWRD + (b0 >> 5);
  bits[t][0] = src[0]; bits[t][1] = src[1];
  __syncthreads();
  const int b = t >> 2, ms = (t & 3) * 64;
  const int wd = b >> 5, sh = b & 31;
  unsigned short* dst = wt + ((size_t)hg * BDIM + b0 + b) * NMEM + m0 + ms;
  #pragma unroll
  for (int j = 0; j < 64; j += 4) {
    ushort4 v;
    v.x = ((bits[ms+j+0][wd] >> sh) & 1) ? 0x3C00 : 0xBC00;
    v.y = ((bits[ms+j+1][wd] >> sh) & 1) ? 0x3C00 : 0xBC00;
    v.z = ((bits[ms+j+2][wd] >> sh) & 1) ? 0x3C00 : 0xBC00;
    v.w = ((bits[ms+j+3][wd] >> sh) & 1) ? 0x3C00 : 0xBC00;
    *(ushort4*)&dst[j] = v;
  }
}

// ------- K5: fused sim (xor+popcount, exact) + softmax numerator -> f16 ----
// Softmax 1/Z cancels in the later per-head L2-normalize -> store p only.
// 1-D grid, head-fast decode so all blocks of a head share one XCD's L2.
// launch_bounds(512,2): 256-VGPR cap so pops[8][8]+code stay in registers.
__global__ __launch_bounds__(512, 2) void k_simsm(const unsigned* __restrict__ code,
    const unsigned* __restrict__ wp, unsigned short* __restrict__ attn,
    int h0, int gmask, int gshift) {
  const int bid = (int)blockIdx.x;
  const int hg = bid & gmask;            // head-fast: XCD = bid%8 = head%8
  const int h  = h0 + hg;
  const int n0 = (bid >> gshift) * 8;
  const int t = threadIdx.x;
  __shared__ unsigned cl[8][16];
  __shared__ float score_t[513];
  __shared__ int   redi[8][8];
  if (t < 128) cl[t >> 4][t & 15] =
      code[(size_t)(h * NTOK + n0 + (t >> 4)) * NWRD + (t & 15)];
  for (int p = t; p < 513; p += 512) {
    float sim = (512.f - 2.f * (float)p) * (1.f / 512.f);
    score_t[p] = cosf(1.57079632679489662f * (1.f - sim));   // same formula as ref
  }
  __syncthreads();
  unsigned pops[8][8];
  const uint4* wv4 = (const uint4*)(wp + (size_t)h * NMEM * NWRD);
  #pragma unroll
  for (int k = 0; k < 16; ++k) {
    const int m = (k << 9) + t;
    uint4 w0 = wv4[(size_t)m*4+0], w1 = wv4[(size_t)m*4+1];
    uint4 w2 = wv4[(size_t)m*4+2], w3 = wv4[(size_t)m*4+3];
    #pragma unroll
    for (int r = 0; r < 8; ++r) {
      const uint4* c4 = (const uint4*)cl[r];
      uint4 c0 = c4[0], c1 = c4[1], c2 = c4[2], c3 = c4[3];
      int pop = __popc(c0.x^w0.x) + __popc(c0.y^w0.y) + __popc(c0.z^w0.z) + __popc(c0.w^w0.w)
              + __popc(c1.x^w1.x) + __popc(c1.y^w1.y) + __popc(c1.z^w1.z) + __popc(c1.w^w1.w)
              + __popc(c2.x^w2.x) + __popc(c2.y^w2.y) + __popc(c2.z^w2.z) + __popc(c2.w^w2.w)
              + __popc(c3.x^w3.x) + __popc(c3.y^w3.y) + __popc(c3.z^w3.z) + __popc(c3.w^w3.w);
      if (k & 1) pops[r][k >> 1] |= (unsigned)pop << 16;
      else       pops[r][k >> 1]  = (unsigned)pop;
    }
  }
  const int lane = t & 63, wid = t >> 6;
  #pragma unroll
  for (int r = 0; r < 8; ++r) {          // min pop == max score
    int mn = 1 << 30;
    #pragma unroll
    for (int kk = 0; kk < 8; ++kk) {
      mn = min(mn, (int)(pops[r][kk] & 0xffffu));
      mn = min(mn, (int)(pops[r][kk] >> 16));
    }
    #pragma unroll
    for (int off = 32; off; off >>= 1) mn = min(mn, __shfl_down(mn, off));
    if (lane == 0) redi[r][wid] = mn;
  }
  __syncthreads();
  float smax[8];
  #pragma unroll
  for (int r = 0; r < 8; ++r) {
    int mn = redi[r][0];
    #pragma unroll
    for (int wv = 1; wv < 8; ++wv) mn = min(mn, redi[r][wv]);
    smax[r] = score_t[mn];
  }
  // store unnormalized p = exp((score - smax)/TEMP); scale cancels later
  #pragma unroll
  for (int k = 0; k < 16; ++k) {
    const int m = (k << 9) + t;
    #pragma unroll
    for (int r = 0; r < 8; ++r) {
      unsigned pv = pops[r][k >> 1];
      int pop = (k & 1) ? (int)(pv >> 16) : (int)(pv & 0xffffu);
      float pr = __expf((score_t[pop] - smax[r]) * 100.f);
      attn[((size_t)hg * NTOK + n0 + r) * NMEM + m] =
          __half_as_ushort(__float2half(pr));
    }
  }
}

// ------- K6: o1^T[hg][b][n] = (p @ w)^T via f16 MFMA, 128x256 tile ---------
// XCD-group decode: the 8 n-tiles sharing one (head, b-half) wt panel all
// land on one XCD so the 4MB B-panel stays L2-resident.
__global__ __launch_bounds__(512, 2) void k_stageF(const unsigned short* __restrict__ attn,
    const unsigned short* __restrict__ wt, float* __restrict__ o1t) {
  __shared__ _Float16 Al[128][72];
  __shared__ _Float16 Bl[256][72];
  const int wg = (int)blockIdx.x;
  const int nb = (int)gridDim.x;        // 16*G
  int hg, bt, nt;
  if (nb >= 64) {                       // G>=4: XCD-grouped decode
    const int x = wg & 7, o = wg >> 3;
    nt = o & 7;
    const int gid = x * (nb >> 6) + (o >> 3);
    hg = gid >> 1; bt = gid & 1;
  } else {
    hg = wg >> 4; bt = (wg >> 3) & 1; nt = wg & 7;
  }
  const int n0 = nt * 128, b0 = bt * 256;
  const int t = threadIdx.x;
  const int lane = t & 63, wid = t >> 6;
  const int wm = wid >> 2, wn = wid & 3;
  f32x4 acc[4][4];
  #pragma unroll
  for (int i = 0; i < 4; ++i)
    #pragma unroll
    for (int j = 0; j < 4; ++j) acc[i][j] = (f32x4){0.f, 0.f, 0.f, 0.f};

  const int ar = t >> 2, as = (t & 3) * 16;
  const int br = t >> 1, bs = (t & 1) * 32;
  const unsigned short* asrc = attn + ((size_t)hg * NTOK + n0 + ar) * NMEM + as;
  const unsigned short* bsrc = wt   + ((size_t)hg * BDIM + b0 + br) * NMEM + bs;

  for (int k0 = 0; k0 < NMEM; k0 += 64) {
    uint4 a0  = *(const uint4*)(asrc + k0);
    uint4 a1  = *(const uint4*)(asrc + k0 + 8);
    uint4 bv0 = *(const uint4*)(bsrc + k0);
    uint4 bv1 = *(const uint4*)(bsrc + k0 + 8);
    uint4 bv2 = *(const uint4*)(bsrc + k0 + 16);
    uint4 bv3 = *(const uint4*)(bsrc + k0 + 24);
    __syncthreads();
    *(uint4*)&Al[ar][as]      = a0;
    *(uint4*)&Al[ar][as + 8]  = a1;
    *(uint4*)&Bl[br][bs]      = bv0;
    *(uint4*)&Bl[br][bs + 8]  = bv1;
    *(uint4*)&Bl[br][bs + 16] = bv2;
    *(uint4*)&Bl[br][bs + 24] = bv3;
    __syncthreads();
    #pragma unroll
    for (int kk = 0; kk < 64; kk += 32) {
      f16x8 af[4], bf[4];
      #pragma unroll
      for (int fm = 0; fm < 4; ++fm)
        af[fm] = *(const f16x8*)&Al[wm*64 + fm*16 + (lane & 15)][kk + (lane >> 4) * 8];
      #pragma unroll
      for (int fn = 0; fn < 4; ++fn)
        bf[fn] = *(const f16x8*)&Bl[wn*64 + fn*16 + (lane & 15)][kk + (lane >> 4) * 8];
      #pragma unroll
      for (int fm = 0; fm < 4; ++fm)
        #pragma unroll
        for (int fn = 0; fn < 4; ++fn)
          acc[fm][fn] = __builtin_amdgcn_mfma_f32_16x16x32_f16(af[fm], bf[fn], acc[fm][fn], 0, 0, 0);
    }
  }
  #pragma unroll
  for (int fm = 0; fm < 4; ++fm) {
    const int rowb = n0 + wm*64 + fm*16 + (lane >> 4) * 4;   // C: row=(l>>4)*4+reg
    #pragma unroll
    for (int fn = 0; fn < 4; ++fn) {
      const int col = b0 + wn*64 + fn*16 + (lane & 15);      // C: col=l&15
      *(f32x4*)&o1t[((size_t)hg * BDIM + col) * NTOK + rowb] = acc[fm][fn];
    }
  }
}

// ------- K7: out[n][h*64+d] = normalize_d( o1 . bin_inv ) ------------------
__global__ __launch_bounds__(256) void k_proj(const float* __restrict__ o1t,
    const float* __restrict__ bT, float* __restrict__ o2, int h0) {
  const int hg = blockIdx.y, h = h0 + hg;
  const int n0 = blockIdx.x * 64;
  __shared__ float bl[128][68];
  __shared__ float ol[128][68];
  __shared__ float outl[64][68];
  __shared__ float nrm[64];
  const int t = threadIdx.x;
  const int tx = t & 15, ty = t >> 4;
  float acc[4][4] = {};
  for (int c = 0; c < 4; ++c) {
    const int bb0 = c * 128;
    __syncthreads();
    #pragma unroll
    for (int i = 0; i < 8; ++i) {
      int fi = t + 256 * i;
      int rr = fi >> 4, cc = (fi & 15) * 4;
      *(float4*)&bl[rr][cc] = *(const float4*)&bT[((size_t)h * BDIM + bb0 + rr) * DH + cc];
      *(float4*)&ol[rr][cc] = *(const float4*)&o1t[((size_t)hg * BDIM + bb0 + rr) * NTOK + n0 + cc];
    }
    __syncthreads();
    for (int bb = 0; bb < 128; ++bb) {
      float4 bd = *(const float4*)&bl[bb][tx * 4];
      float4 on = *(const float4*)&ol[bb][ty * 4];
      float ai[4] = {on.x, on.y, on.z, on.w};
      float bj[4] = {bd.x, bd.y, bd.z, bd.w};
      #pragma unroll
      for (int i = 0; i < 4; ++i)
        #pragma unroll
        for (int j = 0; j < 4; ++j) acc[i][j] += ai[i] * bj[j];
    }
  }
  __syncthreads();
  #pragma unroll
  for (int i = 0; i < 4; ++i)
    #pragma unroll
    for (int j = 0; j < 4; ++j) outl[ty*4 + i][tx*4 + j] = acc[i][j];
  __syncthreads();
  if (t < 64) {
    float s = 0.f;
    #pragma unroll
    for (int d = 0; d < 64; ++d) { float v = outl[t][d]; s += v * v; }
    nrm[t] = 1.f / sqrtf(s);
  }
  __syncthreads();
  {
    const int n = t >> 2, dg = (t & 3) * 16;
    #pragma unroll
    for (int j = 0; j < 16; ++j)
      o2[(size_t)(n0 + n) * OUTF + h * 64 + dg + j] = outl[n][dg + j] * nrm[n];
  }
}

// ------- K8: LayerNorm over 1024 features ----------------------------------
__global__ __launch_bounds__(256) void k_ln(const float* __restrict__ o2,
    const float* __restrict__ lnw, const float* __restrict__ lnb, float* __restrict__ out) {
  const int n = blockIdx.x, t = threadIdx.x;
  __shared__ float red[4];
  float4 v = *(const float4*)&o2[(size_t)n * OUTF + t * 4];
  float s = v.x + v.y + v.z + v.w;
  const int lane = t & 63, wid = t >> 6;
  #pragma unroll
  for (int off = 32; off; off >>= 1) s += __shfl_down(s, off);
  if (lane == 0) red[wid] = s;
  __syncthreads();
  const float mu = (red[0] + red[1] + red[2] + red[3]) * (1.f / 1024.f);
  float4 d = {v.x - mu, v.y - mu, v.z - mu, v.w - mu};
  float s2 = d.x*d.x + d.y*d.y + d.z*d.z + d.w*d.w;
  #pragma unroll
  for (int off = 32; off; off >>= 1) s2 += __shfl_down(s2, off);
  __syncthreads();
  if (lane == 0) red[wid] = s2;
  __syncthreads();
  const float var = (red[0] + red[1] + red[2] + red[3]) * (1.f / 1024.f);
  const float inv = 1.f / sqrtf(var + 1e-5f);
  float4 w = *(const float4*)&lnw[t * 4];
  float4 b = *(const float4*)&lnb[t * 4];
  float4 o = { d.x*inv*w.x + b.x, d.y*inv*w.y + b.y,
               d.z*inv*w.z + b.z, d.w*inv*w.w + b.w };
  *(float4*)&out[(size_t)n * OUTF + t * 4] = o;
}

extern "C" void kernel_launch(void* const* d_in, const int* in_sizes, int n_in,
                              void* d_out, int out_size, void* d_ws, size_t ws_size,
                              hipStream_t stream) {
  (void)in_sizes; (void)n_in; (void)out_size;
  const float* x    = (const float*)d_in[0];
  const float* Wq   = (const float*)d_in[1];
  const float* bq   = (const float*)d_in[2];
  const float* bp   = (const float*)d_in[3];
  const float* binv = (const float*)d_in[4];
  const float* wm   = (const float*)d_in[5];
  const float* lnw  = (const float*)d_in[6];
  const float* lnb  = (const float*)d_in[7];
  float* outp = (float*)d_out;

  char* ws = (char*)d_ws;
  size_t off = 0;
  auto carve = [&](size_t bytes) -> char* {
    char* p = ws + off;
    off += (bytes + 255) & ~(size_t)255;
    return p;
  };
  float*    q    = (float*)   carve((size_t)NTOK * OUTF * 4);
  unsigned* code = (unsigned*)carve((size_t)NH * NTOK * NWRD * 4);
  unsigned* wpk  = (unsigned*)carve((size_t)NH * NMEM * NWRD * 4);
  float*    bT   = (float*)   carve((size_t)NH * BDIM * DH * 4);
  float*    o2   = (float*)   carve((size_t)NTOK * OUTF * 4);
  const size_t fixed = off;
  const size_t per = ((size_t)BDIM * NMEM * 2 + 256)
                   + ((size_t)NTOK * NMEM * 2 + 256)
                   + ((size_t)BDIM * NTOK * 4 + 256);
  int G = 16;
  while (G > 1 && fixed + (size_t)G * per > ws_size) G >>= 1;
  unsigned short* wt   = (unsigned short*)carve((size_t)G * BDIM * NMEM * 2);
  unsigned short* attn = (unsigned short*)carve((size_t)G * NTOK * NMEM * 2);
  float*          o1t  = (float*)         carve((size_t)G * BDIM * NTOK * 4);
  const int gshift = __builtin_ctz(G);

  k_qgemm<<<dim3(16, 16), 256, 0, stream>>>(x, Wq, bq, q);
  k_code <<<dim3(64, 16), 256, 0, stream>>>(q, bp, code);
  k_packw<<<dim3(NH * NMEM / 4), 256, 0, stream>>>(wm, wpk);
  k_binT <<<dim3(8, 16), 256, 0, stream>>>(binv, bT);
  for (int h0 = 0; h0 < NH; h0 += G) {
    k_wt    <<<dim3(32, 8, G), 256, 0, stream>>>(wpk, wt, h0);
    k_simsm <<<dim3(128 * G),  512, 0, stream>>>(code, wpk, attn, h0, G - 1, gshift);
    k_stageF<<<dim3(G * 16),   512, 0, stream>>>(attn, wt, o1t);
    k_proj  <<<dim3(16, G),    256, 0, stream>>>(o1t, bT, o2, h0);
  }
  k_ln<<<dim3(NTOK), 256, 0, stream>>>(o2, lnw, lnb, outp);
}

// Round 3
// 995.393 us; speedup vs baseline: 1.5203x; 1.3961x over previous
//
#include <hip/hip_runtime.h>
#include <hip/hip_fp16.h>

#define NTOK 1024
#define INF  1024
#define NH   16
#define DH   64
#define BDIM 512
#define NMEM 8192
#define OUTF 1024
#define NWRD 16   // 512 bits = 16 u32

typedef _Float16 f16x8 __attribute__((ext_vector_type(8)));
typedef float    f32x4 __attribute__((ext_vector_type(4)));

#define GLOAD16(G, L) __builtin_amdgcn_global_load_lds( \
    (const __attribute__((address_space(1))) unsigned int*)(G), \
    (__attribute__((address_space(3))) unsigned int*)(L), 16, 0, 0)

// ---------------- K1: q = x @ Wq^T + bq (f32, 64x64 tile) ----------------
__global__ __launch_bounds__(256) void k_qgemm(const float* __restrict__ x,
    const float* __restrict__ Wq, const float* __restrict__ bq, float* __restrict__ q) {
  __shared__ float As[64][17];
  __shared__ float Bs[64][17];
  const int tx = threadIdx.x & 15, ty = threadIdx.x >> 4;
  const int n0 = blockIdx.y * 64, o0 = blockIdx.x * 64;
  const int r = threadIdx.x >> 2, c4 = (threadIdx.x & 3) * 4;
  float acc[4][4] = {};
  for (int k0 = 0; k0 < INF; k0 += 16) {
    float4 av = *(const float4*)&x[(size_t)(n0 + r) * INF + k0 + c4];
    float4 bv = *(const float4*)&Wq[(size_t)(o0 + r) * INF + k0 + c4];
    __syncthreads();               // prev compute done before LDS overwrite
    As[r][c4+0] = av.x; As[r][c4+1] = av.y; As[r][c4+2] = av.z; As[r][c4+3] = av.w;
    Bs[r][c4+0] = bv.x; Bs[r][c4+1] = bv.y; Bs[r][c4+2] = bv.z; Bs[r][c4+3] = bv.w;
    __syncthreads();
    #pragma unroll
    for (int kk = 0; kk < 16; ++kk) {
      float a[4], b[4];
      #pragma unroll
      for (int i = 0; i < 4; ++i) a[i] = As[ty*4+i][kk];
      #pragma unroll
      for (int j = 0; j < 4; ++j) b[j] = Bs[tx*4+j][kk];
      #pragma unroll
      for (int i = 0; i < 4; ++i)
        #pragma unroll
        for (int j = 0; j < 4; ++j) acc[i][j] += a[i] * b[j];
    }
  }
  #pragma unroll
  for (int i = 0; i < 4; ++i) {
    const int row = n0 + ty*4 + i;
    #pragma unroll
    for (int j = 0; j < 4; ++j) {
      const int col = o0 + tx*4 + j;
      q[(size_t)row * OUTF + col] = acc[i][j] + bq[col];
    }
  }
}

// ---------------- K2: code = sign(q . bin_proj), bit-packed ----------------
// norm of q doesn't change sign -> skip normalization entirely
__global__ __launch_bounds__(256) void k_code(const float* __restrict__ q,
    const float* __restrict__ bp, unsigned* __restrict__ code) {
  const int h = blockIdx.y, n0 = blockIdx.x * 16;
  __shared__ float ql[16][68];
  const int t = threadIdx.x;
  {
    const int r = t >> 4, c = (t & 15) * 4;
    float4 v = *(const float4*)&q[(size_t)(n0 + r) * OUTF + h * 64 + c];
    ql[r][c] = v.x; ql[r][c+1] = v.y; ql[r][c+2] = v.z; ql[r][c+3] = v.w;
  }
  __syncthreads();
  const int lane = t & 63, wv = t >> 6;
  #pragma unroll
  for (int bb = 0; bb < 512; bb += 256) {
    const int b = bb + t;
    float bpv[64];
    const float4* src = (const float4*)&bp[((size_t)h * BDIM + b) * 64];
    #pragma unroll
    for (int j = 0; j < 16; ++j) {
      float4 v = src[j];
      bpv[j*4] = v.x; bpv[j*4+1] = v.y; bpv[j*4+2] = v.z; bpv[j*4+3] = v.w;
    }
    const int w0 = (bb + wv * 64) >> 5;
    for (int n = 0; n < 16; ++n) {
      float dot = 0.f;
      #pragma unroll
      for (int d = 0; d < 64; ++d) dot += bpv[d] * ql[n][d];
      unsigned long long msk = __ballot(dot > 0.f);
      if (lane == 0) {
        code[(size_t)(h * NTOK + n0 + n) * NWRD + w0]     = (unsigned)msk;
        code[(size_t)(h * NTOK + n0 + n) * NWRD + w0 + 1] = (unsigned)(msk >> 32);
      }
    }
  }
}

// ---------------- K3: pack weight_matrix signs into bits (wave per row) ----
__global__ __launch_bounds__(256) void k_packw(const float* __restrict__ w,
                                               unsigned* __restrict__ wp) {
  const int row  = blockIdx.x * 4 + (threadIdx.x >> 6);
  const int lane = threadIdx.x & 63;
  const float* src = w + (size_t)row * BDIM;
  unsigned my = 0;
  #pragma unroll
  for (int kk = 0; kk < 8; ++kk) {
    float v = src[kk * 64 + lane];
    unsigned long long m = __ballot(v > 0.f);
    if ((lane >> 1) == kk) my = (lane & 1) ? (unsigned)(m >> 32) : (unsigned)m;
  }
  if (lane < 16) wp[(size_t)row * NWRD + lane] = my;
}

// ---------------- K3b: transpose bin_inv [h][d][b] -> binT [h][b][d] -------
__global__ __launch_bounds__(256) void k_binT(const float* __restrict__ binv,
                                              float* __restrict__ bT) {
  const int h = blockIdx.y, b0 = blockIdx.x * 64;
  __shared__ float tl[64][65];
  const int t = threadIdx.x;
  #pragma unroll
  for (int i = 0; i < 4; ++i) {
    int fi = t + 256 * i;
    int d = fi >> 4, b = (fi & 15) * 4;
    float4 v = *(const float4*)&binv[((size_t)h * DH + d) * BDIM + b0 + b];
    tl[d][b] = v.x; tl[d][b+1] = v.y; tl[d][b+2] = v.z; tl[d][b+3] = v.w;
  }
  __syncthreads();
  #pragma unroll
  for (int i = 0; i < 4; ++i) {
    int fo = t + 256 * i;
    int bb = fo >> 4, dd = (fo & 15) * 4;
    float4 v = { tl[dd][bb], tl[dd+1][bb], tl[dd+2][bb], tl[dd+3][bb] };
    *(float4*)&bT[((size_t)h * BDIM + b0 + bb) * DH + dd] = v;
  }
}

// ---------------- K4: expand bits -> f16 w_t [hg][b][m] (+-1) --------------
__global__ __launch_bounds__(256) void k_wt(const unsigned* __restrict__ wp,
    unsigned short* __restrict__ wt, int h0) {
  const int hg = blockIdx.z, h = h0 + hg;
  const int b0 = blockIdx.y * 64, m0 = blockIdx.x * 256;
  __shared__ unsigned bits[256][2];
  const int t = threadIdx.x;
  const unsigned* src = wp + (size_t)(h * NMEM + m0 + t) * NWRD + (b0 >> 5);
  bits[t][0] = src[0]; bits[t][1] = src[1];
  __syncthreads();
  const int b = t >> 2, ms = (t & 3) * 64;
  const int wd = b >> 5, sh = b & 31;
  unsigned short* dst = wt + ((size_t)hg * BDIM + b0 + b) * NMEM + m0 + ms;
  #pragma unroll
  for (int j = 0; j < 64; j += 4) {
    ushort4 v;
    v.x = ((bits[ms+j+0][wd] >> sh) & 1) ? 0x3C00 : 0xBC00;
    v.y = ((bits[ms+j+1][wd] >> sh) & 1) ? 0x3C00 : 0xBC00;
    v.z = ((bits[ms+j+2][wd] >> sh) & 1) ? 0x3C00 : 0xBC00;
    v.w = ((bits[ms+j+3][wd] >> sh) & 1) ? 0x3C00 : 0xBC00;
    *(ushort4*)&dst[j] = v;
  }
}

// ------- K5: two-pass sim (xor+popcount) + softmax numerator -> f16 --------
// Block = 16 rows of one head, 8 waves; wave owns 4 rows x 4096 memories.
// Codes live in SGPRs (readfirstlane) -> tiny VGPR footprint, NO spill,
// no LDS reads in the hot loop. Pass1: min-pop. Pass2: recompute + exp2.
// Softmax 1/Z cancels in the later per-head L2-normalize -> store p only.
__global__ __launch_bounds__(512) void k_simsm(const unsigned* __restrict__ code,
    const unsigned* __restrict__ wp, unsigned short* __restrict__ attn,
    int h0, int gmask, int gshift) {
  const int bid = (int)blockIdx.x;
  const int hg = bid & gmask, h = h0 + hg;      // head-fast: XCD = head%8
  const int n0 = (bid >> gshift) * 16;
  const int t = threadIdx.x, lane = t & 63, wid = t >> 6;
  const int rg = wid >> 1;                      // row-group (4 rows)
  const int mh = wid & 1;                       // memory half
  __shared__ float sc2[513];
  __shared__ int redi[8][4];
  for (int p = t; p < 513; p += 512) {
    float sim = (512.f - 2.f * (float)p) * (1.f / 512.f);
    // 100/TEMP-scaled, pre-multiplied by log2(e) for v_exp_f32
    sc2[p] = 144.2695040889f * cosf(1.57079632679489662f * (1.f - sim));
  }
  unsigned cw[4][16];
  #pragma unroll
  for (int r = 0; r < 4; ++r)
    #pragma unroll
    for (int j = 0; j < 16; ++j)
      cw[r][j] = __builtin_amdgcn_readfirstlane(
          code[((size_t)h * NTOK + n0 + rg * 4 + r) * NWRD + j]);
  __syncthreads();
  const uint4* wv4 = (const uint4*)(wp + (size_t)h * NMEM * NWRD);
  const int mbase = mh * 4096;
  int mn[4] = {1 << 30, 1 << 30, 1 << 30, 1 << 30};
  #pragma unroll 2
  for (int i = 0; i < 64; ++i) {
    const int m = mbase + i * 64 + lane;
    uint4 w0 = wv4[(size_t)m*4+0], w1 = wv4[(size_t)m*4+1];
    uint4 w2 = wv4[(size_t)m*4+2], w3 = wv4[(size_t)m*4+3];
    #pragma unroll
    for (int r = 0; r < 4; ++r) {
      int pop = __popc(w0.x^cw[r][0])  + __popc(w0.y^cw[r][1])
              + __popc(w0.z^cw[r][2])  + __popc(w0.w^cw[r][3])
              + __popc(w1.x^cw[r][4])  + __popc(w1.y^cw[r][5])
              + __popc(w1.z^cw[r][6])  + __popc(w1.w^cw[r][7])
              + __popc(w2.x^cw[r][8])  + __popc(w2.y^cw[r][9])
              + __popc(w2.z^cw[r][10]) + __popc(w2.w^cw[r][11])
              + __popc(w3.x^cw[r][12]) + __popc(w3.y^cw[r][13])
              + __popc(w3.z^cw[r][14]) + __popc(w3.w^cw[r][15]);
      mn[r] = min(mn[r], pop);
    }
  }
  #pragma unroll
  for (int r = 0; r < 4; ++r) {
    #pragma unroll
    for (int off = 32; off; off >>= 1) mn[r] = min(mn[r], __shfl_down(mn[r], off));
  }
  if (lane == 0) {
    #pragma unroll
    for (int r = 0; r < 4; ++r) redi[wid][r] = mn[r];
  }
  __syncthreads();
  float sm2[4];
  #pragma unroll
  for (int r = 0; r < 4; ++r)
    sm2[r] = sc2[min(redi[rg * 2][r], redi[rg * 2 + 1][r])];
  unsigned short* arow0 = attn + ((size_t)hg * NTOK + n0 + rg * 4) * NMEM + mbase;
  #pragma unroll 2
  for (int i = 0; i < 64; ++i) {
    const int m = mbase + i * 64 + lane;
    uint4 w0 = wv4[(size_t)m*4+0], w1 = wv4[(size_t)m*4+1];
    uint4 w2 = wv4[(size_t)m*4+2], w3 = wv4[(size_t)m*4+3];
    #pragma unroll
    for (int r = 0; r < 4; ++r) {
      int pop = __popc(w0.x^cw[r][0])  + __popc(w0.y^cw[r][1])
              + __popc(w0.z^cw[r][2])  + __popc(w0.w^cw[r][3])
              + __popc(w1.x^cw[r][4])  + __popc(w1.y^cw[r][5])
              + __popc(w1.z^cw[r][6])  + __popc(w1.w^cw[r][7])
              + __popc(w2.x^cw[r][8])  + __popc(w2.y^cw[r][9])
              + __popc(w2.z^cw[r][10]) + __popc(w2.w^cw[r][11])
              + __popc(w3.x^cw[r][12]) + __popc(w3.y^cw[r][13])
              + __popc(w3.z^cw[r][14]) + __popc(w3.w^cw[r][15]);
      float p = exp2f(sc2[pop] - sm2[r]);
      arow0[(size_t)r * NMEM + i * 64 + lane] = __half_as_ushort(__float2half(p));
    }
  }
}

// ------- K6: o1^T[hg][b][n] = (p @ w)^T via f16 MFMA, 128x256 tile ---------
// Linear LDS + global_load_lds(16B) staging (m97 structure).
__global__ __launch_bounds__(512, 2) void k_stageF(const unsigned short* __restrict__ attn,
    const unsigned short* __restrict__ wt, float* __restrict__ o1t) {
  __shared__ _Float16 Al[128][64];
  __shared__ _Float16 Bl[256][64];
  const int wg = (int)blockIdx.x;
  const int nb = (int)gridDim.x;        // 16*G
  int hg, bt, nt;
  if (nb >= 64) {                       // G>=4: XCD-grouped decode
    const int x = wg & 7, o = wg >> 3;
    nt = o & 7;
    const int gid = x * (nb >> 6) + (o >> 3);
    hg = gid >> 1; bt = gid & 1;
  } else {
    hg = wg >> 4; bt = (wg >> 3) & 1; nt = wg & 7;
  }
  const int n0 = nt * 128, b0 = bt * 256;
  const int t = threadIdx.x;
  const int lane = t & 63, wid = t >> 6;
  const int wm = wid >> 2, wn = wid & 3;
  f32x4 acc[4][4];
  #pragma unroll
  for (int i = 0; i < 4; ++i)
    #pragma unroll
    for (int j = 0; j < 4; ++j) acc[i][j] = (f32x4){0.f, 0.f, 0.f, 0.f};

  // staging: wave w fills Al rows [16w,16w+16) (2 fills) and Bl rows
  // [32w,32w+32) (4 fills); each fill = 64 lanes x 16B = 8 rows x 128B.
  const unsigned short* ag = attn + ((size_t)hg * NTOK + n0 + 16*wid + (lane >> 3)) * NMEM + (lane & 7) * 8;
  const unsigned short* bg = wt   + ((size_t)hg * BDIM + b0 + 32*wid + (lane >> 3)) * NMEM + (lane & 7) * 8;
  _Float16* al0 = &Al[16 * wid][0];     // wave-uniform LDS bases
  _Float16* bl0 = &Bl[32 * wid][0];

  for (int k0 = 0; k0 < NMEM; k0 += 64) {
    __syncthreads();                    // previous tile fully consumed
    GLOAD16(ag,             al0);
    GLOAD16(ag +  8 * NMEM, al0 +  8 * 64);
    GLOAD16(bg,             bl0);
    GLOAD16(bg +  8 * NMEM, bl0 +  8 * 64);
    GLOAD16(bg + 16 * NMEM, bl0 + 16 * 64);
    GLOAD16(bg + 24 * NMEM, bl0 + 24 * 64);
    ag += 64; bg += 64;
    __syncthreads();                    // drains vmcnt -> LDS ready
    #pragma unroll
    for (int kk = 0; kk < 64; kk += 32) {
      f16x8 af[4], bf[4];
      #pragma unroll
      for (int fm = 0; fm < 4; ++fm)
        af[fm] = *(const f16x8*)&Al[wm*64 + fm*16 + (lane & 15)][kk + (lane >> 4) * 8];
      #pragma unroll
      for (int fn = 0; fn < 4; ++fn)
        bf[fn] = *(const f16x8*)&Bl[wn*64 + fn*16 + (lane & 15)][kk + (lane >> 4) * 8];
      #pragma unroll
      for (int fm = 0; fm < 4; ++fm)
        #pragma unroll
        for (int fn = 0; fn < 4; ++fn)
          acc[fm][fn] = __builtin_amdgcn_mfma_f32_16x16x32_f16(af[fm], bf[fn], acc[fm][fn], 0, 0, 0);
    }
  }
  #pragma unroll
  for (int fm = 0; fm < 4; ++fm) {
    const int rowb = n0 + wm*64 + fm*16 + (lane >> 4) * 4;   // C: row=(l>>4)*4+reg
    #pragma unroll
    for (int fn = 0; fn < 4; ++fn) {
      const int col = b0 + wn*64 + fn*16 + (lane & 15);      // C: col=l&15
      *(f32x4*)&o1t[((size_t)hg * BDIM + col) * NTOK + rowb] = acc[fm][fn];
    }
  }
}

// ------- K7: out[n][h*64+d] = normalize_d( o1 . bin_inv ) ------------------
__global__ __launch_bounds__(256) void k_proj(const float* __restrict__ o1t,
    const float* __restrict__ bT, float* __restrict__ o2, int h0) {
  const int hg = blockIdx.y, h = h0 + hg;
  const int n0 = blockIdx.x * 64;
  __shared__ float bl[128][68];
  __shared__ float ol[128][68];
  __shared__ float outl[64][68];
  __shared__ float nrm[64];
  const int t = threadIdx.x;
  const int tx = t & 15, ty = t >> 4;
  float acc[4][4] = {};
  for (int c = 0; c < 4; ++c) {
    const int bb0 = c * 128;
    __syncthreads();
    #pragma unroll
    for (int i = 0; i < 8; ++i) {
      int fi = t + 256 * i;
      int rr = fi >> 4, cc = (fi & 15) * 4;
      *(float4*)&bl[rr][cc] = *(const float4*)&bT[((size_t)h * BDIM + bb0 + rr) * DH + cc];
      *(float4*)&ol[rr][cc] = *(const float4*)&o1t[((size_t)hg * BDIM + bb0 + rr) * NTOK + n0 + cc];
    }
    __syncthreads();
    for (int bb = 0; bb < 128; ++bb) {
      float4 bd = *(const float4*)&bl[bb][tx * 4];
      float4 on = *(const float4*)&ol[bb][ty * 4];
      float ai[4] = {on.x, on.y, on.z, on.w};
      float bj[4] = {bd.x, bd.y, bd.z, bd.w};
      #pragma unroll
      for (int i = 0; i < 4; ++i)
        #pragma unroll
        for (int j = 0; j < 4; ++j) acc[i][j] += ai[i] * bj[j];
    }
  }
  __syncthreads();
  #pragma unroll
  for (int i = 0; i < 4; ++i)
    #pragma unroll
    for (int j = 0; j < 4; ++j) outl[ty*4 + i][tx*4 + j] = acc[i][j];
  __syncthreads();
  if (t < 64) {
    float s = 0.f;
    #pragma unroll
    for (int d = 0; d < 64; ++d) { float v = outl[t][d]; s += v * v; }
    nrm[t] = 1.f / sqrtf(s);
  }
  __syncthreads();
  {
    const int n = t >> 2, dg = (t & 3) * 16;
    #pragma unroll
    for (int j = 0; j < 16; ++j)
      o2[(size_t)(n0 + n) * OUTF + h * 64 + dg + j] = outl[n][dg + j] * nrm[n];
  }
}

// ------- K8: LayerNorm over 1024 features ----------------------------------
__global__ __launch_bounds__(256) void k_ln(const float* __restrict__ o2,
    const float* __restrict__ lnw, const float* __restrict__ lnb, float* __restrict__ out) {
  const int n = blockIdx.x, t = threadIdx.x;
  __shared__ float red[4];
  float4 v = *(const float4*)&o2[(size_t)n * OUTF + t * 4];
  float s = v.x + v.y + v.z + v.w;
  const int lane = t & 63, wid = t >> 6;
  #pragma unroll
  for (int off = 32; off; off >>= 1) s += __shfl_down(s, off);
  if (lane == 0) red[wid] = s;
  __syncthreads();
  const float mu = (red[0] + red[1] + red[2] + red[3]) * (1.f / 1024.f);
  float4 d = {v.x - mu, v.y - mu, v.z - mu, v.w - mu};
  float s2 = d.x*d.x + d.y*d.y + d.z*d.z + d.w*d.w;
  #pragma unroll
  for (int off = 32; off; off >>= 1) s2 += __shfl_down(s2, off);
  __syncthreads();
  if (lane == 0) red[wid] = s2;
  __syncthreads();
  const float var = (red[0] + red[1] + red[2] + red[3]) * (1.f / 1024.f);
  const float inv = 1.f / sqrtf(var + 1e-5f);
  float4 w = *(const float4*)&lnw[t * 4];
  float4 b = *(const float4*)&lnb[t * 4];
  float4 o = { d.x*inv*w.x + b.x, d.y*inv*w.y + b.y,
               d.z*inv*w.z + b.z, d.w*inv*w.w + b.w };
  *(float4*)&out[(size_t)n * OUTF + t * 4] = o;
}

extern "C" void kernel_launch(void* const* d_in, const int* in_sizes, int n_in,
                              void* d_out, int out_size, void* d_ws, size_t ws_size,
                              hipStream_t stream) {
  (void)in_sizes; (void)n_in; (void)out_size;
  const float* x    = (const float*)d_in[0];
  const float* Wq   = (const float*)d_in[1];
  const float* bq   = (const float*)d_in[2];
  const float* bp   = (const float*)d_in[3];
  const float* binv = (const float*)d_in[4];
  const float* wm   = (const float*)d_in[5];
  const float* lnw  = (const float*)d_in[6];
  const float* lnb  = (const float*)d_in[7];
  float* outp = (float*)d_out;

  char* ws = (char*)d_ws;
  size_t off = 0;
  auto carve = [&](size_t bytes) -> char* {
    char* p = ws + off;
    off += (bytes + 255) & ~(size_t)255;
    return p;
  };
  float*    q    = (float*)   carve((size_t)NTOK * OUTF * 4);
  unsigned* code = (unsigned*)carve((size_t)NH * NTOK * NWRD * 4);
  unsigned* wpk  = (unsigned*)carve((size_t)NH * NMEM * NWRD * 4);
  float*    bT   = (float*)   carve((size_t)NH * BDIM * DH * 4);
  float*    o2   = (float*)   carve((size_t)NTOK * OUTF * 4);
  const size_t fixed = off;
  const size_t per = ((size_t)BDIM * NMEM * 2 + 256)
                   + ((size_t)NTOK * NMEM * 2 + 256)
                   + ((size_t)BDIM * NTOK * 4 + 256);
  int G = 16;
  while (G > 1 && fixed + (size_t)G * per > ws_size) G >>= 1;
  unsigned short* wt   = (unsigned short*)carve((size_t)G * BDIM * NMEM * 2);
  unsigned short* attn = (unsigned short*)carve((size_t)G * NTOK * NMEM * 2);
  float*          o1t  = (float*)         carve((size_t)G * BDIM * NTOK * 4);
  const int gshift = __builtin_ctz(G);

  k_qgemm<<<dim3(16, 16), 256, 0, stream>>>(x, Wq, bq, q);
  k_code <<<dim3(64, 16), 256, 0, stream>>>(q, bp, code);
  k_packw<<<dim3(NH * NMEM / 4), 256, 0, stream>>>(wm, wpk);
  k_binT <<<dim3(8, 16), 256, 0, stream>>>(binv, bT);
  for (int h0 = 0; h0 < NH; h0 += G) {
    k_wt    <<<dim3(32, 8, G), 256, 0, stream>>>(wpk, wt, h0);
    k_simsm <<<dim3(64 * G),   512, 0, stream>>>(code, wpk, attn, h0, G - 1, gshift);
    k_stageF<<<dim3(G * 16),   512, 0, stream>>>(attn, wt, o1t);
    k_proj  <<<dim3(16, G),    256, 0, stream>>>(o1t, bT, o2, h0);
  }
  k_ln<<<dim3(NTOK), 256, 0, stream>>>(o2, lnw, lnb, outp);
}

// Round 4
// 990.351 us; speedup vs baseline: 1.5280x; 1.0051x over previous
//
#include <hip/hip_runtime.h>
#include <hip/hip_fp16.h>

#define NTOK 1024
#define INF  1024
#define NH   16
#define DH   64
#define BDIM 512
#define NMEM 8192
#define OUTF 1024
#define NWRD 16   // 512 bits = 16 u32

typedef _Float16 f16x8 __attribute__((ext_vector_type(8)));
typedef float    f32x4 __attribute__((ext_vector_type(4)));
typedef int      i32x4 __attribute__((ext_vector_type(4)));

#define GLOAD16(G, L) __builtin_amdgcn_global_load_lds( \
    (const __attribute__((address_space(1))) unsigned int*)(G), \
    (__attribute__((address_space(3))) unsigned int*)(L), 16, 0, 0)

// ---------------- K1: q = x @ Wq^T + bq (f32, 64x64 tile) ----------------
__global__ __launch_bounds__(256) void k_qgemm(const float* __restrict__ x,
    const float* __restrict__ Wq, const float* __restrict__ bq, float* __restrict__ q) {
  __shared__ float As[64][17];
  __shared__ float Bs[64][17];
  const int tx = threadIdx.x & 15, ty = threadIdx.x >> 4;
  const int n0 = blockIdx.y * 64, o0 = blockIdx.x * 64;
  const int r = threadIdx.x >> 2, c4 = (threadIdx.x & 3) * 4;
  float acc[4][4] = {};
  for (int k0 = 0; k0 < INF; k0 += 16) {
    float4 av = *(const float4*)&x[(size_t)(n0 + r) * INF + k0 + c4];
    float4 bv = *(const float4*)&Wq[(size_t)(o0 + r) * INF + k0 + c4];
    __syncthreads();               // prev compute done before LDS overwrite
    As[r][c4+0] = av.x; As[r][c4+1] = av.y; As[r][c4+2] = av.z; As[r][c4+3] = av.w;
    Bs[r][c4+0] = bv.x; Bs[r][c4+1] = bv.y; Bs[r][c4+2] = bv.z; Bs[r][c4+3] = bv.w;
    __syncthreads();
    #pragma unroll
    for (int kk = 0; kk < 16; ++kk) {
      float a[4], b[4];
      #pragma unroll
      for (int i = 0; i < 4; ++i) a[i] = As[ty*4+i][kk];
      #pragma unroll
      for (int j = 0; j < 4; ++j) b[j] = Bs[tx*4+j][kk];
      #pragma unroll
      for (int i = 0; i < 4; ++i)
        #pragma unroll
        for (int j = 0; j < 4; ++j) acc[i][j] += a[i] * b[j];
    }
  }
  #pragma unroll
  for (int i = 0; i < 4; ++i) {
    const int row = n0 + ty*4 + i;
    #pragma unroll
    for (int j = 0; j < 4; ++j) {
      const int col = o0 + tx*4 + j;
      q[(size_t)row * OUTF + col] = acc[i][j] + bq[col];
    }
  }
}

// ---------------- K2: code_i8 = sign(q . bin_proj) as +-1 i8 ---------------
// norm of q doesn't change sign -> skip normalization entirely
__global__ __launch_bounds__(256) void k_code(const float* __restrict__ q,
    const float* __restrict__ bp, signed char* __restrict__ code_i8) {
  const int h = blockIdx.y, n0 = blockIdx.x * 16;
  __shared__ float ql[16][68];
  const int t = threadIdx.x;
  {
    const int r = t >> 4, c = (t & 15) * 4;
    float4 v = *(const float4*)&q[(size_t)(n0 + r) * OUTF + h * 64 + c];
    ql[r][c] = v.x; ql[r][c+1] = v.y; ql[r][c+2] = v.z; ql[r][c+3] = v.w;
  }
  __syncthreads();
  #pragma unroll
  for (int bb = 0; bb < 512; bb += 256) {
    const int b = bb + t;
    float bpv[64];
    const float4* src = (const float4*)&bp[((size_t)h * BDIM + b) * 64];
    #pragma unroll
    for (int j = 0; j < 16; ++j) {
      float4 v = src[j];
      bpv[j*4] = v.x; bpv[j*4+1] = v.y; bpv[j*4+2] = v.z; bpv[j*4+3] = v.w;
    }
    for (int n = 0; n < 16; ++n) {
      float dot = 0.f;
      #pragma unroll
      for (int d = 0; d < 64; ++d) dot += bpv[d] * ql[n][d];
      code_i8[((size_t)h * NTOK + n0 + n) * BDIM + b] = dot > 0.f ? 1 : -1;
    }
  }
}

// -------- K3: weight_matrix -> sign bits (for k_wt) AND +-1 i8 -------------
__global__ __launch_bounds__(256) void k_packw(const float* __restrict__ w,
    unsigned* __restrict__ wp, signed char* __restrict__ w_i8) {
  const int row  = blockIdx.x * 4 + (threadIdx.x >> 6);
  const int lane = threadIdx.x & 63;
  const float* src = w + (size_t)row * BDIM;
  unsigned my = 0;
  #pragma unroll
  for (int kk = 0; kk < 8; ++kk) {
    float v = src[kk * 64 + lane];
    w_i8[(size_t)row * BDIM + kk * 64 + lane] = v > 0.f ? 1 : -1;
    unsigned long long m = __ballot(v > 0.f);
    if ((lane >> 1) == kk) my = (lane & 1) ? (unsigned)(m >> 32) : (unsigned)m;
  }
  if (lane < 16) wp[(size_t)row * NWRD + lane] = my;
}

// ---------------- K3b: transpose bin_inv [h][d][b] -> binT [h][b][d] -------
__global__ __launch_bounds__(256) void k_binT(const float* __restrict__ binv,
                                              float* __restrict__ bT) {
  const int h = blockIdx.y, b0 = blockIdx.x * 64;
  __shared__ float tl[64][65];
  const int t = threadIdx.x;
  #pragma unroll
  for (int i = 0; i < 4; ++i) {
    int fi = t + 256 * i;
    int d = fi >> 4, b = (fi & 15) * 4;
    float4 v = *(const float4*)&binv[((size_t)h * DH + d) * BDIM + b0 + b];
    tl[d][b] = v.x; tl[d][b+1] = v.y; tl[d][b+2] = v.z; tl[d][b+3] = v.w;
  }
  __syncthreads();
  #pragma unroll
  for (int i = 0; i < 4; ++i) {
    int fo = t + 256 * i;
    int bb = fo >> 4, dd = (fo & 15) * 4;
    float4 v = { tl[dd][bb], tl[dd+1][bb], tl[dd+2][bb], tl[dd+3][bb] };
    *(float4*)&bT[((size_t)h * BDIM + b0 + bb) * DH + dd] = v;
  }
}

// ---------------- K4: expand bits -> f16 w_t [hg][b][m] (+-1) --------------
__global__ __launch_bounds__(256) void k_wt(const unsigned* __restrict__ wp,
    unsigned short* __restrict__ wt, int h0) {
  const int hg = blockIdx.z, h = h0 + hg;
  const int b0 = blockIdx.y * 64, m0 = blockIdx.x * 256;
  __shared__ unsigned bits[256][2];
  const int t = threadIdx.x;
  const unsigned* src = wp + (size_t)(h * NMEM + m0 + t) * NWRD + (b0 >> 5);
  bits[t][0] = src[0]; bits[t][1] = src[1];
  __syncthreads();
  const int b = t >> 2, ms = (t & 3) * 64;
  const int wd = b >> 5, sh = b & 31;
  unsigned short* dst = wt + ((size_t)hg * BDIM + b0 + b) * NMEM + m0 + ms;
  #pragma unroll
  for (int j = 0; j < 64; j += 4) {
    ushort4 v;
    v.x = ((bits[ms+j+0][wd] >> sh) & 1) ? 0x3C00 : 0xBC00;
    v.y = ((bits[ms+j+1][wd] >> sh) & 1) ? 0x3C00 : 0xBC00;
    v.z = ((bits[ms+j+2][wd] >> sh) & 1) ? 0x3C00 : 0xBC00;
    v.w = ((bits[ms+j+3][wd] >> sh) & 1) ? 0x3C00 : 0xBC00;
    *(ushort4*)&dst[j] = v;
  }
}

// ------- K5: sim = code_i8 @ w_i8^T via i8 MFMA; writes sim i16 + row max --
// Block: one head, 32 query rows, 512 thr (8 waves m-striped over 8192).
// A fragments (32x512 i8) live wholly in VGPRs; B streamed from L2.
__global__ __launch_bounds__(512, 2) void k_sim(const signed char* __restrict__ code_i8,
    const signed char* __restrict__ w_i8, short* __restrict__ simb,
    int* __restrict__ rowmax, int h0, int gmask, int gshift) {
  const int bid = (int)blockIdx.x;
  const int hg = bid & gmask, h = h0 + hg;      // head-fast: XCD window small
  const int n0 = (bid >> gshift) * 32;
  const int t = threadIdx.x, lane = t & 63, wid = t >> 6;
  __shared__ int smaxl[32];
  if (t < 32) smaxl[t] = -(1 << 30);
  // A frags: [fi][kk]: row = n0 + fi*16 + (lane&15), k = kk*64 + (lane>>4)*16
  i32x4 afrag[2][8];
  #pragma unroll
  for (int fi = 0; fi < 2; ++fi)
    #pragma unroll
    for (int kk = 0; kk < 8; ++kk)
      afrag[fi][kk] = *(const i32x4*)(code_i8 +
          ((size_t)h * NTOK + n0 + fi * 16 + (lane & 15)) * BDIM +
          kk * 64 + (lane >> 4) * 16);
  __syncthreads();
  int vmax[2][4];
  #pragma unroll
  for (int fi = 0; fi < 2; ++fi)
    #pragma unroll
    for (int j = 0; j < 4; ++j) vmax[fi][j] = -(1 << 30);
  const signed char* bbase0 = w_i8 + (size_t)h * NMEM * BDIM +
                              (lane & 15) * BDIM + (lane >> 4) * 16;
  for (int i = 0; i < 32; ++i) {
    const int m0 = (i * 8 + wid) * 32;           // block-consecutive m window
    const signed char* bb = bbase0 + (size_t)m0 * BDIM;
    i32x4 acc[2][2] = {};
    #pragma unroll
    for (int kk = 0; kk < 8; ++kk) {
      i32x4 b0 = *(const i32x4*)(bb + kk * 64);
      i32x4 b1 = *(const i32x4*)(bb + 16 * BDIM + kk * 64);
      acc[0][0] = __builtin_amdgcn_mfma_i32_16x16x64_i8(afrag[0][kk], b0, acc[0][0], 0, 0, 0);
      acc[0][1] = __builtin_amdgcn_mfma_i32_16x16x64_i8(afrag[0][kk], b1, acc[0][1], 0, 0, 0);
      acc[1][0] = __builtin_amdgcn_mfma_i32_16x16x64_i8(afrag[1][kk], b0, acc[1][0], 0, 0, 0);
      acc[1][1] = __builtin_amdgcn_mfma_i32_16x16x64_i8(afrag[1][kk], b1, acc[1][1], 0, 0, 0);
    }
    #pragma unroll
    for (int fi = 0; fi < 2; ++fi)
      #pragma unroll
      for (int j = 0; j < 4; ++j) {
        const int row = n0 + fi * 16 + (lane >> 4) * 4 + j;  // C: row=(l>>4)*4+reg
        short* dst = simb + ((size_t)hg * NTOK + row) * NMEM + m0 + (lane & 15);
        const int v0 = acc[fi][0][j], v1 = acc[fi][1][j];
        dst[0]  = (short)v0;                                  // C: col=l&15
        dst[16] = (short)v1;
        vmax[fi][j] = max(vmax[fi][j], max(v0, v1));
      }
  }
  #pragma unroll
  for (int fi = 0; fi < 2; ++fi)
    #pragma unroll
    for (int j = 0; j < 4; ++j) {
      int v = vmax[fi][j];
      #pragma unroll
      for (int s = 1; s < 16; s <<= 1) v = max(v, __shfl_xor(v, s));
      if ((lane & 15) == 0)
        atomicMax(&smaxl[fi * 16 + (lane >> 4) * 4 + j], v);
    }
  __syncthreads();
  if (t < 32) rowmax[(size_t)hg * NTOK + n0 + t] = smaxl[t];
}

// ------- K5b: attn f16 = exp2(sc2[sim] - sc2[rowmax]) (streaming) ----------
// Softmax 1/Z cancels in the later per-head L2-normalize -> numerator only.
__global__ __launch_bounds__(256) void k_exp(const short* __restrict__ simb,
    const int* __restrict__ rowmax, unsigned short* __restrict__ attn) {
  __shared__ float sc2[513];
  const int t = threadIdx.x;
  for (int p = t; p < 513; p += 256) {
    float sim = (2.f * (float)p - 512.f) * (1.f / 512.f);
    // score/TEMP pre-multiplied by log2(e) for v_exp_f32
    sc2[p] = 144.2695040889f * cosf(1.57079632679489662f * (1.f - sim));
  }
  __syncthreads();
  const int row = blockIdx.x * 4 + (t >> 6);
  const int lane = t & 63;
  const float sm2 = sc2[(rowmax[row] + 512) >> 1];
  const short* src = simb + (size_t)row * NMEM;
  unsigned short* dst = attn + (size_t)row * NMEM;
  for (int it = 0; it < 16; ++it) {
    const int base = it * 512 + lane * 8;
    uint4 sv = *(const uint4*)(src + base);
    unsigned ov[4];
    #pragma unroll
    for (int k = 0; k < 4; ++k) {
      const unsigned w = (&sv.x)[k];
      const int lo = (int)(short)(w & 0xffffu);
      const int hi = (int)(short)(w >> 16);
      float p0 = exp2f(sc2[(lo + 512) >> 1] - sm2);
      float p1 = exp2f(sc2[(hi + 512) >> 1] - sm2);
      ov[k] = (unsigned)__half_as_ushort(__float2half(p0))
            | ((unsigned)__half_as_ushort(__float2half(p1)) << 16);
    }
    *(uint4*)(dst + base) = make_uint4(ov[0], ov[1], ov[2], ov[3]);
  }
}

// ------- K6: o1^T[hg][b][n] = (p @ w)^T via f16 MFMA, 128x256 tile ---------
// Linear LDS + global_load_lds(16B) staging (m97 structure).
__global__ __launch_bounds__(512, 2) void k_stageF(const unsigned short* __restrict__ attn,
    const unsigned short* __restrict__ wt, float* __restrict__ o1t) {
  __shared__ _Float16 Al[128][64];
  __shared__ _Float16 Bl[256][64];
  const int wg = (int)blockIdx.x;
  const int nb = (int)gridDim.x;        // 16*G
  int hg, bt, nt;
  if (nb >= 64) {                       // G>=4: XCD-grouped decode
    const int x = wg & 7, o = wg >> 3;
    nt = o & 7;
    const int gid = x * (nb >> 6) + (o >> 3);
    hg = gid >> 1; bt = gid & 1;
  } else {
    hg = wg >> 4; bt = (wg >> 3) & 1; nt = wg & 7;
  }
  const int n0 = nt * 128, b0 = bt * 256;
  const int t = threadIdx.x;
  const int lane = t & 63, wid = t >> 6;
  const int wm = wid >> 2, wn = wid & 3;
  f32x4 acc[4][4];
  #pragma unroll
  for (int i = 0; i < 4; ++i)
    #pragma unroll
    for (int j = 0; j < 4; ++j) acc[i][j] = (f32x4){0.f, 0.f, 0.f, 0.f};

  // staging: wave w fills Al rows [16w,16w+16) (2 fills) and Bl rows
  // [32w,32w+32) (4 fills); each fill = 64 lanes x 16B = 8 rows x 128B.
  const unsigned short* ag = attn + ((size_t)hg * NTOK + n0 + 16*wid + (lane >> 3)) * NMEM + (lane & 7) * 8;
  const unsigned short* bg = wt   + ((size_t)hg * BDIM + b0 + 32*wid + (lane >> 3)) * NMEM + (lane & 7) * 8;
  _Float16* al0 = &Al[16 * wid][0];     // wave-uniform LDS bases
  _Float16* bl0 = &Bl[32 * wid][0];

  for (int k0 = 0; k0 < NMEM; k0 += 64) {
    __syncthreads();                    // previous tile fully consumed
    GLOAD16(ag,             al0);
    GLOAD16(ag +  8 * NMEM, al0 +  8 * 64);
    GLOAD16(bg,             bl0);
    GLOAD16(bg +  8 * NMEM, bl0 +  8 * 64);
    GLOAD16(bg + 16 * NMEM, bl0 + 16 * 64);
    GLOAD16(bg + 24 * NMEM, bl0 + 24 * 64);
    ag += 64; bg += 64;
    __syncthreads();                    // drains vmcnt -> LDS ready
    #pragma unroll
    for (int kk = 0; kk < 64; kk += 32) {
      f16x8 af[4], bf[4];
      #pragma unroll
      for (int fm = 0; fm < 4; ++fm)
        af[fm] = *(const f16x8*)&Al[wm*64 + fm*16 + (lane & 15)][kk + (lane >> 4) * 8];
      #pragma unroll
      for (int fn = 0; fn < 4; ++fn)
        bf[fn] = *(const f16x8*)&Bl[wn*64 + fn*16 + (lane & 15)][kk + (lane >> 4) * 8];
      #pragma unroll
      for (int fm = 0; fm < 4; ++fm)
        #pragma unroll
        for (int fn = 0; fn < 4; ++fn)
          acc[fm][fn] = __builtin_amdgcn_mfma_f32_16x16x32_f16(af[fm], bf[fn], acc[fm][fn], 0, 0, 0);
    }
  }
  #pragma unroll
  for (int fm = 0; fm < 4; ++fm) {
    const int rowb = n0 + wm*64 + fm*16 + (lane >> 4) * 4;   // C: row=(l>>4)*4+reg
    #pragma unroll
    for (int fn = 0; fn < 4; ++fn) {
      const int col = b0 + wn*64 + fn*16 + (lane & 15);      // C: col=l&15
      *(f32x4*)&o1t[((size_t)hg * BDIM + col) * NTOK + rowb] = acc[fm][fn];
    }
  }
}

// ------- K7: out[n][h*64+d] = normalize_d( o1 . bin_inv ) ------------------
__global__ __launch_bounds__(256) void k_proj(const float* __restrict__ o1t,
    const float* __restrict__ bT, float* __restrict__ o2, int h0) {
  const int hg = blockIdx.y, h = h0 + hg;
  const int n0 = blockIdx.x * 64;
  __shared__ float bl[128][68];
  __shared__ float ol[128][68];
  __shared__ float outl[64][68];
  __shared__ float nrm[64];
  const int t = threadIdx.x;
  const int tx = t & 15, ty = t >> 4;
  float acc[4][4] = {};
  for (int c = 0; c < 4; ++c) {
    const int bb0 = c * 128;
    __syncthreads();
    #pragma unroll
    for (int i = 0; i < 8; ++i) {
      int fi = t + 256 * i;
      int rr = fi >> 4, cc = (fi & 15) * 4;
      *(float4*)&bl[rr][cc] = *(const float4*)&bT[((size_t)h * BDIM + bb0 + rr) * DH + cc];
      *(float4*)&ol[rr][cc] = *(const float4*)&o1t[((size_t)hg * BDIM + bb0 + rr) * NTOK + n0 + cc];
    }
    __syncthreads();
    for (int bb = 0; bb < 128; ++bb) {
      float4 bd = *(const float4*)&bl[bb][tx * 4];
      float4 on = *(const float4*)&ol[bb][ty * 4];
      float ai[4] = {on.x, on.y, on.z, on.w};
      float bj[4] = {bd.x, bd.y, bd.z, bd.w};
      #pragma unroll
      for (int i = 0; i < 4; ++i)
        #pragma unroll
        for (int j = 0; j < 4; ++j) acc[i][j] += ai[i] * bj[j];
    }
  }
  __syncthreads();
  #pragma unroll
  for (int i = 0; i < 4; ++i)
    #pragma unroll
    for (int j = 0; j < 4; ++j) outl[ty*4 + i][tx*4 + j] = acc[i][j];
  __syncthreads();
  if (t < 64) {
    float s = 0.f;
    #pragma unroll
    for (int d = 0; d < 64; ++d) { float v = outl[t][d]; s += v * v; }
    nrm[t] = 1.f / sqrtf(s);
  }
  __syncthreads();
  {
    const int n = t >> 2, dg = (t & 3) * 16;
    #pragma unroll
    for (int j = 0; j < 16; ++j)
      o2[(size_t)(n0 + n) * OUTF + h * 64 + dg + j] = outl[n][dg + j] * nrm[n];
  }
}

// ------- K8: LayerNorm over 1024 features ----------------------------------
__global__ __launch_bounds__(256) void k_ln(const float* __restrict__ o2,
    const float* __restrict__ lnw, const float* __restrict__ lnb, float* __restrict__ out) {
  const int n = blockIdx.x, t = threadIdx.x;
  __shared__ float red[4];
  float4 v = *(const float4*)&o2[(size_t)n * OUTF + t * 4];
  float s = v.x + v.y + v.z + v.w;
  const int lane = t & 63, wid = t >> 6;
  #pragma unroll
  for (int off = 32; off; off >>= 1) s += __shfl_down(s, off);
  if (lane == 0) red[wid] = s;
  __syncthreads();
  const float mu = (red[0] + red[1] + red[2] + red[3]) * (1.f / 1024.f);
  float4 d = {v.x - mu, v.y - mu, v.z - mu, v.w - mu};
  float s2 = d.x*d.x + d.y*d.y + d.z*d.z + d.w*d.w;
  #pragma unroll
  for (int off = 32; off; off >>= 1) s2 += __shfl_down(s2, off);
  __syncthreads();
  if (lane == 0) red[wid] = s2;
  __syncthreads();
  const float var = (red[0] + red[1] + red[2] + red[3]) * (1.f / 1024.f);
  const float inv = 1.f / sqrtf(var + 1e-5f);
  float4 w = *(const float4*)&lnw[t * 4];
  float4 b = *(const float4*)&lnb[t * 4];
  float4 o = { d.x*inv*w.x + b.x, d.y*inv*w.y + b.y,
               d.z*inv*w.z + b.z, d.w*inv*w.w + b.w };
  *(float4*)&out[(size_t)n * OUTF + t * 4] = o;
}

extern "C" void kernel_launch(void* const* d_in, const int* in_sizes, int n_in,
                              void* d_out, int out_size, void* d_ws, size_t ws_size,
                              hipStream_t stream) {
  (void)in_sizes; (void)n_in; (void)out_size;
  const float* x    = (const float*)d_in[0];
  const float* Wq   = (const float*)d_in[1];
  const float* bq   = (const float*)d_in[2];
  const float* bp   = (const float*)d_in[3];
  const float* binv = (const float*)d_in[4];
  const float* wm   = (const float*)d_in[5];
  const float* lnw  = (const float*)d_in[6];
  const float* lnb  = (const float*)d_in[7];
  float* outp = (float*)d_out;

  char* ws = (char*)d_ws;
  size_t off = 0;
  auto carve = [&](size_t bytes) -> char* {
    char* p = ws + off;
    off += (bytes + 255) & ~(size_t)255;
    return p;
  };
  float*       q       = (float*)      carve((size_t)NTOK * OUTF * 4);
  signed char* code_i8 = (signed char*)carve((size_t)NH * NTOK * BDIM);
  unsigned*    wpk     = (unsigned*)   carve((size_t)NH * NMEM * NWRD * 4);
  signed char* w_i8    = (signed char*)carve((size_t)NH * NMEM * BDIM);
  float*       bT      = (float*)      carve((size_t)NH * BDIM * DH * 4);
  float*       o2      = (float*)      carve((size_t)NTOK * OUTF * 4);
  const size_t fixed = off;
  const size_t per = ((size_t)BDIM * NMEM * 2 + 256)    // wt
                   + ((size_t)NTOK * NMEM * 2 + 256)    // attn
                   + ((size_t)NTOK * NMEM * 2 + 256)    // sim i16
                   + ((size_t)BDIM * NTOK * 4 + 256)    // o1t
                   + ((size_t)NTOK * 4 + 256);          // rowmax
  int G = 16;
  while (G > 1 && fixed + (size_t)G * per > ws_size) G >>= 1;
  unsigned short* wt   = (unsigned short*)carve((size_t)G * BDIM * NMEM * 2);
  unsigned short* attn = (unsigned short*)carve((size_t)G * NTOK * NMEM * 2);
  short*          simb = (short*)         carve((size_t)G * NTOK * NMEM * 2);
  float*          o1t  = (float*)         carve((size_t)G * BDIM * NTOK * 4);
  int*            rmax = (int*)           carve((size_t)G * NTOK * 4);
  const int gshift = __builtin_ctz(G);

  k_qgemm<<<dim3(16, 16), 256, 0, stream>>>(x, Wq, bq, q);
  k_code <<<dim3(64, 16), 256, 0, stream>>>(q, bp, code_i8);
  k_packw<<<dim3(NH * NMEM / 4), 256, 0, stream>>>(wm, wpk, w_i8);
  k_binT <<<dim3(8, 16), 256, 0, stream>>>(binv, bT);
  for (int h0 = 0; h0 < NH; h0 += G) {
    k_wt    <<<dim3(32, 8, G), 256, 0, stream>>>(wpk, wt, h0);
    k_sim   <<<dim3(32 * G),   512, 0, stream>>>(code_i8, w_i8, simb, rmax, h0, G - 1, gshift);
    k_exp   <<<dim3(G * 256),  256, 0, stream>>>(simb, rmax, attn);
    k_stageF<<<dim3(G * 16),   512, 0, stream>>>(attn, wt, o1t);
    k_proj  <<<dim3(16, G),    256, 0, stream>>>(o1t, bT, o2, h0);
  }
  k_ln<<<dim3(NTOK), 256, 0, stream>>>(o2, lnw, lnb, outp);
}

// Round 5
// 756.110 us; speedup vs baseline: 2.0014x; 1.3098x over previous
//
#include <hip/hip_runtime.h>
#include <hip/hip_fp16.h>

#define NTOK 1024
#define INF  1024
#define NH   16
#define DH   64
#define BDIM 512
#define NMEM 8192
#define OUTF 1024
#define NWRD 16   // 512 bits = 16 u32

typedef _Float16 f16x8 __attribute__((ext_vector_type(8)));
typedef float    f32x4 __attribute__((ext_vector_type(4)));
typedef int      i32x4 __attribute__((ext_vector_type(4)));

#define GLOAD16(G, L) __builtin_amdgcn_global_load_lds( \
    (const __attribute__((address_space(1))) unsigned int*)(G), \
    (__attribute__((address_space(3))) unsigned int*)(L), 16, 0, 0)

// score*100/TEMP... score/TEMP * log2(e):  cos(pi/2*(1-s/512)) == sin(pi/2*s/512)
__device__ inline float score2(float s) {
  return 144.2695040889f * __sinf(s * 0.0030679615757712823f);
}

// ---------------- K1: q = x @ Wq^T + bq (f32, 64x64 tile) ----------------
__global__ __launch_bounds__(256) void k_qgemm(const float* __restrict__ x,
    const float* __restrict__ Wq, const float* __restrict__ bq, float* __restrict__ q) {
  __shared__ float As[64][17];
  __shared__ float Bs[64][17];
  const int tx = threadIdx.x & 15, ty = threadIdx.x >> 4;
  const int n0 = blockIdx.y * 64, o0 = blockIdx.x * 64;
  const int r = threadIdx.x >> 2, c4 = (threadIdx.x & 3) * 4;
  float acc[4][4] = {};
  for (int k0 = 0; k0 < INF; k0 += 16) {
    float4 av = *(const float4*)&x[(size_t)(n0 + r) * INF + k0 + c4];
    float4 bv = *(const float4*)&Wq[(size_t)(o0 + r) * INF + k0 + c4];
    __syncthreads();               // prev compute done before LDS overwrite
    As[r][c4+0] = av.x; As[r][c4+1] = av.y; As[r][c4+2] = av.z; As[r][c4+3] = av.w;
    Bs[r][c4+0] = bv.x; Bs[r][c4+1] = bv.y; Bs[r][c4+2] = bv.z; Bs[r][c4+3] = bv.w;
    __syncthreads();
    #pragma unroll
    for (int kk = 0; kk < 16; ++kk) {
      float a[4], b[4];
      #pragma unroll
      for (int i = 0; i < 4; ++i) a[i] = As[ty*4+i][kk];
      #pragma unroll
      for (int j = 0; j < 4; ++j) b[j] = Bs[tx*4+j][kk];
      #pragma unroll
      for (int i = 0; i < 4; ++i)
        #pragma unroll
        for (int j = 0; j < 4; ++j) acc[i][j] += a[i] * b[j];
    }
  }
  #pragma unroll
  for (int i = 0; i < 4; ++i) {
    const int row = n0 + ty*4 + i;
    #pragma unroll
    for (int j = 0; j < 4; ++j) {
      const int col = o0 + tx*4 + j;
      q[(size_t)row * OUTF + col] = acc[i][j] + bq[col];
    }
  }
}

// ---------------- K2: code_i8 = sign(q . bin_proj) as +-1 i8 ---------------
// norm of q doesn't change sign -> skip normalization entirely
__global__ __launch_bounds__(256) void k_code(const float* __restrict__ q,
    const float* __restrict__ bp, signed char* __restrict__ code_i8) {
  const int h = blockIdx.y, n0 = blockIdx.x * 16;
  __shared__ float ql[16][68];
  const int t = threadIdx.x;
  {
    const int r = t >> 4, c = (t & 15) * 4;
    float4 v = *(const float4*)&q[(size_t)(n0 + r) * OUTF + h * 64 + c];
    ql[r][c] = v.x; ql[r][c+1] = v.y; ql[r][c+2] = v.z; ql[r][c+3] = v.w;
  }
  __syncthreads();
  #pragma unroll
  for (int bb = 0; bb < 512; bb += 256) {
    const int b = bb + t;
    float bpv[64];
    const float4* src = (const float4*)&bp[((size_t)h * BDIM + b) * 64];
    #pragma unroll
    for (int j = 0; j < 16; ++j) {
      float4 v = src[j];
      bpv[j*4] = v.x; bpv[j*4+1] = v.y; bpv[j*4+2] = v.z; bpv[j*4+3] = v.w;
    }
    for (int n = 0; n < 16; ++n) {
      float dot = 0.f;
      #pragma unroll
      for (int d = 0; d < 64; ++d) dot += bpv[d] * ql[n][d];
      code_i8[((size_t)h * NTOK + n0 + n) * BDIM + b] = dot > 0.f ? 1 : -1;
    }
  }
}

// -------- K3: weight_matrix -> sign bits (for k_wt) AND +-1 i8 -------------
__global__ __launch_bounds__(256) void k_packw(const float* __restrict__ w,
    unsigned* __restrict__ wp, signed char* __restrict__ w_i8) {
  const int row  = blockIdx.x * 4 + (threadIdx.x >> 6);
  const int lane = threadIdx.x & 63;
  const float* src = w + (size_t)row * BDIM;
  unsigned my = 0;
  #pragma unroll
  for (int kk = 0; kk < 8; ++kk) {
    float v = src[kk * 64 + lane];
    w_i8[(size_t)row * BDIM + kk * 64 + lane] = v > 0.f ? 1 : -1;
    unsigned long long m = __ballot(v > 0.f);
    if ((lane >> 1) == kk) my = (lane & 1) ? (unsigned)(m >> 32) : (unsigned)m;
  }
  if (lane < 16) wp[(size_t)row * NWRD + lane] = my;
}

// ---------------- K3b: transpose bin_inv [h][d][b] -> binT [h][b][d] -------
__global__ __launch_bounds__(256) void k_binT(const float* __restrict__ binv,
                                              float* __restrict__ bT) {
  const int h = blockIdx.y, b0 = blockIdx.x * 64;
  __shared__ float tl[64][65];
  const int t = threadIdx.x;
  #pragma unroll
  for (int i = 0; i < 4; ++i) {
    int fi = t + 256 * i;
    int d = fi >> 4, b = (fi & 15) * 4;
    float4 v = *(const float4*)&binv[((size_t)h * DH + d) * BDIM + b0 + b];
    tl[d][b] = v.x; tl[d][b+1] = v.y; tl[d][b+2] = v.z; tl[d][b+3] = v.w;
  }
  __syncthreads();
  #pragma unroll
  for (int i = 0; i < 4; ++i) {
    int fo = t + 256 * i;
    int bb = fo >> 4, dd = (fo & 15) * 4;
    float4 v = { tl[dd][bb], tl[dd+1][bb], tl[dd+2][bb], tl[dd+3][bb] };
    *(float4*)&bT[((size_t)h * BDIM + b0 + bb) * DH + dd] = v;
  }
}

// ------- K4: expand bits -> f16 wt [hg][b][m] (+-1), PRE-SWIZZLED ----------
// Within each 128B (64-m) window, 16B chunk g stores logical chunk g^(b&7),
// so stageF's linear global_load_lds + swizzled ds_read are conflict-free.
__global__ __launch_bounds__(256) void k_wt(const unsigned* __restrict__ wp,
    unsigned short* __restrict__ wt, int h0) {
  const int hg = blockIdx.z, h = h0 + hg;
  const int b0 = blockIdx.y * 64, m0 = blockIdx.x * 256;
  __shared__ unsigned bits[256][2];
  const int t = threadIdx.x;
  const unsigned* src = wp + (size_t)(h * NMEM + m0 + t) * NWRD + (b0 >> 5);
  bits[t][0] = src[0]; bits[t][1] = src[1];
  __syncthreads();
  const int b = t >> 2, ms = (t & 3) * 64;
  const int wd = b >> 5, sh = b & 31;
  const int bx7 = b & 7;
  unsigned short* dst = wt + ((size_t)hg * BDIM + b0 + b) * NMEM + m0 + ms;
  #pragma unroll
  for (int g = 0; g < 8; ++g) {
    const int pg = g ^ bx7;
    const int j = ms + g * 8;
    ushort4 v0, v1;
    v0.x = ((bits[j+0][wd] >> sh) & 1) ? 0x3C00 : 0xBC00;
    v0.y = ((bits[j+1][wd] >> sh) & 1) ? 0x3C00 : 0xBC00;
    v0.z = ((bits[j+2][wd] >> sh) & 1) ? 0x3C00 : 0xBC00;
    v0.w = ((bits[j+3][wd] >> sh) & 1) ? 0x3C00 : 0xBC00;
    v1.x = ((bits[j+4][wd] >> sh) & 1) ? 0x3C00 : 0xBC00;
    v1.y = ((bits[j+5][wd] >> sh) & 1) ? 0x3C00 : 0xBC00;
    v1.z = ((bits[j+6][wd] >> sh) & 1) ? 0x3C00 : 0xBC00;
    v1.w = ((bits[j+7][wd] >> sh) & 1) ? 0x3C00 : 0xBC00;
    *(ushort4*)&dst[pg * 8]     = v0;
    *(ushort4*)&dst[pg * 8 + 4] = v1;
  }
}

// ------- K5: sim = code_i8 @ w_i8^T via i8 MFMA; sim i16 + row max ---------
// Block: one head, 64 query rows, 8 waves m-striped over all 8192 memories
// (all-m per block => exact rowmax in one pass). Head-fast XCD mapping.
__global__ __launch_bounds__(512, 2) void k_sim(const signed char* __restrict__ code_i8,
    const signed char* __restrict__ w_i8, short* __restrict__ simb,
    int* __restrict__ rowmax, int h0, int gmask, int gshift) {
  const int bid = (int)blockIdx.x;
  const int hg = bid & gmask, h = h0 + hg;      // XCD = bid%8 = h%8
  const int n0 = (bid >> gshift) * 64;
  const int t = threadIdx.x, lane = t & 63, wid = t >> 6;
  __shared__ int smaxl[64];
  if (t < 64) smaxl[t] = -(1 << 30);
  // A frags: row = n0 + fi*16 + (lane&15), k = kk*64 + (lane>>4)*16
  i32x4 afrag[4][8];
  #pragma unroll
  for (int fi = 0; fi < 4; ++fi)
    #pragma unroll
    for (int kk = 0; kk < 8; ++kk)
      afrag[fi][kk] = *(const i32x4*)(code_i8 +
          ((size_t)h * NTOK + n0 + fi * 16 + (lane & 15)) * BDIM +
          kk * 64 + (lane >> 4) * 16);
  __syncthreads();
  int vmax[4][4];
  #pragma unroll
  for (int fi = 0; fi < 4; ++fi)
    #pragma unroll
    for (int j = 0; j < 4; ++j) vmax[fi][j] = -(1 << 30);
  const signed char* bbase0 = w_i8 + (size_t)h * NMEM * BDIM +
                              (lane & 15) * BDIM + (lane >> 4) * 16;
  for (int i = 0; i < 32; ++i) {
    const int m0 = (i * 8 + wid) * 32;
    const signed char* bb = bbase0 + (size_t)m0 * BDIM;
    i32x4 acc[4][2] = {};
    #pragma unroll
    for (int kk = 0; kk < 8; ++kk) {
      i32x4 b0 = *(const i32x4*)(bb + kk * 64);
      i32x4 b1 = *(const i32x4*)(bb + 16 * BDIM + kk * 64);
      #pragma unroll
      for (int fi = 0; fi < 4; ++fi) {
        acc[fi][0] = __builtin_amdgcn_mfma_i32_16x16x64_i8(afrag[fi][kk], b0, acc[fi][0], 0, 0, 0);
        acc[fi][1] = __builtin_amdgcn_mfma_i32_16x16x64_i8(afrag[fi][kk], b1, acc[fi][1], 0, 0, 0);
      }
    }
    #pragma unroll
    for (int fi = 0; fi < 4; ++fi)
      #pragma unroll
      for (int j = 0; j < 4; ++j) {
        const int row = n0 + fi * 16 + (lane >> 4) * 4 + j;   // C: row=(l>>4)*4+reg
        short* dst = simb + ((size_t)hg * NTOK + row) * NMEM + m0 + (lane & 15);
        const int v0 = acc[fi][0][j], v1 = acc[fi][1][j];
        dst[0]  = (short)v0;                                   // C: col=l&15
        dst[16] = (short)v1;
        vmax[fi][j] = max(vmax[fi][j], max(v0, v1));
      }
  }
  #pragma unroll
  for (int fi = 0; fi < 4; ++fi)
    #pragma unroll
    for (int j = 0; j < 4; ++j) {
      int v = vmax[fi][j];
      #pragma unroll
      for (int s = 1; s < 16; s <<= 1) v = max(v, __shfl_xor(v, s));
      if ((lane & 15) == 0)
        atomicMax(&smaxl[fi * 16 + (lane >> 4) * 4 + j], v);
    }
  __syncthreads();
  if (t < 64) rowmax[(size_t)hg * NTOK + n0 + t] = smaxl[t];
}

// ------- K6: o1^T = (exp2(score(sim)-sm) @ wt)^T, f16 MFMA 128x128 ---------
// exp fused into A-staging (reg-staged, swizzled ds_write); B linear
// global_load_lds of pre-swizzled wt; all LDS reads XOR-deswizzled.
__global__ __launch_bounds__(512, 2) void k_stageF(const short* __restrict__ simb,
    const int* __restrict__ rowmax, const unsigned short* __restrict__ wt,
    float* __restrict__ o1t, int gmask, int gshift) {
  __shared__ _Float16 Al[128][64];
  __shared__ _Float16 Bl[128][64];
  const int wg = (int)blockIdx.x;
  const int hg = wg & gmask;                   // XCD = wg%8 = hg%8
  const int rest = wg >> gshift;
  const int nt = rest & 7, bt = rest >> 3;
  const int n0 = nt * 128, b0 = bt * 128;
  const int t = threadIdx.x;
  const int lane = t & 63, wid = t >> 6;
  const int wm = wid >> 2, wn = wid & 3;
  f32x4 acc[4][2];
  #pragma unroll
  for (int i = 0; i < 4; ++i)
    #pragma unroll
    for (int j = 0; j < 2; ++j) acc[i][j] = (f32x4){0.f, 0.f, 0.f, 0.f};

  // A: reg-staged. lane covers rows rA0=16w+(l>>3), rA0+8; chunk l&7.
  const int rA0 = 16 * wid + (lane >> 3);
  const short* ag0 = simb + ((size_t)hg * NTOK + n0 + rA0) * NMEM + (lane & 7) * 8;
  const float sm0 = score2((float)rowmax[(size_t)hg * NTOK + n0 + rA0]);
  const float sm1 = score2((float)rowmax[(size_t)hg * NTOK + n0 + rA0 + 8]);
  const int awp = ((lane & 7) ^ ((lane >> 3) & 7)) * 8;   // swizzled write chunk
  // B: linear gload of pre-swizzled wt. lane deposits at +lane*16B.
  const unsigned short* bg = wt + ((size_t)hg * BDIM + b0 + 16 * wid + (lane >> 3)) * NMEM + (lane & 7) * 8;
  _Float16* bl0 = &Bl[16 * wid][0];            // wave-uniform base

  uint4 sA0 = *(const uint4*)(ag0);
  uint4 sA1 = *(const uint4*)(ag0 + 8 * NMEM);

  for (int k0 = 0; k0 < NMEM; k0 += 64) {
    f16x8 p0, p1;
    const short* s0p = (const short*)&sA0;
    const short* s1p = (const short*)&sA1;
    #pragma unroll
    for (int e = 0; e < 8; ++e) {
      p0[e] = (_Float16)exp2f(score2((float)s0p[e]) - sm0);
      p1[e] = (_Float16)exp2f(score2((float)s1p[e]) - sm1);
    }
    __syncthreads();                  // prev tile fully consumed
    *(f16x8*)&Al[rA0][awp]     = p0;
    *(f16x8*)&Al[rA0 + 8][awp] = p1;
    GLOAD16(bg + k0,            bl0);
    GLOAD16(bg + k0 + 8 * NMEM, bl0 + 8 * 64);
    __syncthreads();                  // drains lgkm + vm -> tile ready
    if (k0 + 64 < NMEM) {             // prefetch next A during MFMA phase
      sA0 = *(const uint4*)(ag0 + k0 + 64);
      sA1 = *(const uint4*)(ag0 + k0 + 64 + 8 * NMEM);
    }
    #pragma unroll
    for (int kk = 0; kk < 64; kk += 32) {
      const int phys = (((kk >> 3) + (lane >> 4)) ^ (lane & 7)) * 8;
      f16x8 af[4], bf[2];
      #pragma unroll
      for (int fm = 0; fm < 4; ++fm)
        af[fm] = *(const f16x8*)&Al[wm*64 + fm*16 + (lane & 15)][phys];
      #pragma unroll
      for (int fn = 0; fn < 2; ++fn)
        bf[fn] = *(const f16x8*)&Bl[wn*32 + fn*16 + (lane & 15)][phys];
      #pragma unroll
      for (int fm = 0; fm < 4; ++fm)
        #pragma unroll
        for (int fn = 0; fn < 2; ++fn)
          acc[fm][fn] = __builtin_amdgcn_mfma_f32_16x16x32_f16(af[fm], bf[fn], acc[fm][fn], 0, 0, 0);
    }
  }
  #pragma unroll
  for (int fm = 0; fm < 4; ++fm) {
    const int rowb = n0 + wm*64 + fm*16 + (lane >> 4) * 4;   // C: row=(l>>4)*4+reg
    #pragma unroll
    for (int fn = 0; fn < 2; ++fn) {
      const int col = b0 + wn*32 + fn*16 + (lane & 15);      // C: col=l&15
      *(f32x4*)&o1t[((size_t)hg * BDIM + col) * NTOK + rowb] = acc[fm][fn];
    }
  }
}

// ------- K7: out[n][h*64+d] = normalize_d( o1 . bin_inv ) ------------------
__global__ __launch_bounds__(256) void k_proj(const float* __restrict__ o1t,
    const float* __restrict__ bT, float* __restrict__ o2, int h0) {
  const int hg = blockIdx.y, h = h0 + hg;
  const int n0 = blockIdx.x * 64;
  __shared__ float bl[128][68];
  __shared__ float ol[128][68];
  __shared__ float outl[64][68];
  __shared__ float nrm[64];
  const int t = threadIdx.x;
  const int tx = t & 15, ty = t >> 4;
  float acc[4][4] = {};
  for (int c = 0; c < 4; ++c) {
    const int bb0 = c * 128;
    __syncthreads();
    #pragma unroll
    for (int i = 0; i < 8; ++i) {
      int fi = t + 256 * i;
      int rr = fi >> 4, cc = (fi & 15) * 4;
      *(float4*)&bl[rr][cc] = *(const float4*)&bT[((size_t)h * BDIM + bb0 + rr) * DH + cc];
      *(float4*)&ol[rr][cc] = *(const float4*)&o1t[((size_t)hg * BDIM + bb0 + rr) * NTOK + n0 + cc];
    }
    __syncthreads();
    for (int bb = 0; bb < 128; ++bb) {
      float4 bd = *(const float4*)&bl[bb][tx * 4];
      float4 on = *(const float4*)&ol[bb][ty * 4];
      float ai[4] = {on.x, on.y, on.z, on.w};
      float bj[4] = {bd.x, bd.y, bd.z, bd.w};
      #pragma unroll
      for (int i = 0; i < 4; ++i)
        #pragma unroll
        for (int j = 0; j < 4; ++j) acc[i][j] += ai[i] * bj[j];
    }
  }
  __syncthreads();
  #pragma unroll
  for (int i = 0; i < 4; ++i)
    #pragma unroll
    for (int j = 0; j < 4; ++j) outl[ty*4 + i][tx*4 + j] = acc[i][j];
  __syncthreads();
  if (t < 64) {
    float s = 0.f;
    #pragma unroll
    for (int d = 0; d < 64; ++d) { float v = outl[t][d]; s += v * v; }
    nrm[t] = 1.f / sqrtf(s);
  }
  __syncthreads();
  {
    const int n = t >> 2, dg = (t & 3) * 16;
    #pragma unroll
    for (int j = 0; j < 16; ++j)
      o2[(size_t)(n0 + n) * OUTF + h * 64 + dg + j] = outl[n][dg + j] * nrm[n];
  }
}

// ------- K8: LayerNorm over 1024 features ----------------------------------
__global__ __launch_bounds__(256) void k_ln(const float* __restrict__ o2,
    const float* __restrict__ lnw, const float* __restrict__ lnb, float* __restrict__ out) {
  const int n = blockIdx.x, t = threadIdx.x;
  __shared__ float red[4];
  float4 v = *(const float4*)&o2[(size_t)n * OUTF + t * 4];
  float s = v.x + v.y + v.z + v.w;
  const int lane = t & 63, wid = t >> 6;
  #pragma unroll
  for (int off = 32; off; off >>= 1) s += __shfl_down(s, off);
  if (lane == 0) red[wid] = s;
  __syncthreads();
  const float mu = (red[0] + red[1] + red[2] + red[3]) * (1.f / 1024.f);
  float4 d = {v.x - mu, v.y - mu, v.z - mu, v.w - mu};
  float s2 = d.x*d.x + d.y*d.y + d.z*d.z + d.w*d.w;
  #pragma unroll
  for (int off = 32; off; off >>= 1) s2 += __shfl_down(s2, off);
  __syncthreads();
  if (lane == 0) red[wid] = s2;
  __syncthreads();
  const float var = (red[0] + red[1] + red[2] + red[3]) * (1.f / 1024.f);
  const float inv = 1.f / sqrtf(var + 1e-5f);
  float4 w = *(const float4*)&lnw[t * 4];
  float4 b = *(const float4*)&lnb[t * 4];
  float4 o = { d.x*inv*w.x + b.x, d.y*inv*w.y + b.y,
               d.z*inv*w.z + b.z, d.w*inv*w.w + b.w };
  *(float4*)&out[(size_t)n * OUTF + t * 4] = o;
}

extern "C" void kernel_launch(void* const* d_in, const int* in_sizes, int n_in,
                              void* d_out, int out_size, void* d_ws, size_t ws_size,
                              hipStream_t stream) {
  (void)in_sizes; (void)n_in; (void)out_size;
  const float* x    = (const float*)d_in[0];
  const float* Wq   = (const float*)d_in[1];
  const float* bq   = (const float*)d_in[2];
  const float* bp   = (const float*)d_in[3];
  const float* binv = (const float*)d_in[4];
  const float* wm   = (const float*)d_in[5];
  const float* lnw  = (const float*)d_in[6];
  const float* lnb  = (const float*)d_in[7];
  float* outp = (float*)d_out;

  char* ws = (char*)d_ws;
  size_t off = 0;
  auto carve = [&](size_t bytes) -> char* {
    char* p = ws + off;
    off += (bytes + 255) & ~(size_t)255;
    return p;
  };
  float*       q       = (float*)      carve((size_t)NTOK * OUTF * 4);
  signed char* code_i8 = (signed char*)carve((size_t)NH * NTOK * BDIM);
  unsigned*    wpk     = (unsigned*)   carve((size_t)NH * NMEM * NWRD * 4);
  signed char* w_i8    = (signed char*)carve((size_t)NH * NMEM * BDIM);
  float*       bT      = (float*)      carve((size_t)NH * BDIM * DH * 4);
  float*       o2      = (float*)      carve((size_t)NTOK * OUTF * 4);
  const size_t fixed = off;
  const size_t per = ((size_t)BDIM * NMEM * 2 + 256)    // wt
                   + ((size_t)NTOK * NMEM * 2 + 256)    // sim i16
                   + ((size_t)BDIM * NTOK * 4 + 256)    // o1t
                   + ((size_t)NTOK * 4 + 256);          // rowmax
  int G = 16;
  while (G > 1 && fixed + (size_t)G * per > ws_size) G >>= 1;
  unsigned short* wt   = (unsigned short*)carve((size_t)G * BDIM * NMEM * 2);
  short*          simb = (short*)         carve((size_t)G * NTOK * NMEM * 2);
  float*          o1t  = (float*)         carve((size_t)G * BDIM * NTOK * 4);
  int*            rmax = (int*)           carve((size_t)G * NTOK * 4);
  const int gshift = __builtin_ctz(G);

  k_qgemm<<<dim3(16, 16), 256, 0, stream>>>(x, Wq, bq, q);
  k_code <<<dim3(64, 16), 256, 0, stream>>>(q, bp, code_i8);
  k_packw<<<dim3(NH * NMEM / 4), 256, 0, stream>>>(wm, wpk, w_i8);
  k_binT <<<dim3(8, 16), 256, 0, stream>>>(binv, bT);
  for (int h0 = 0; h0 < NH; h0 += G) {
    k_wt    <<<dim3(32, 8, G), 256, 0, stream>>>(wpk, wt, h0);
    k_sim   <<<dim3(16 * G),   512, 0, stream>>>(code_i8, w_i8, simb, rmax, h0, G - 1, gshift);
    k_stageF<<<dim3(32 * G),   512, 0, stream>>>(simb, rmax, wt, o1t, G - 1, gshift);
    k_proj  <<<dim3(16, G),    256, 0, stream>>>(o1t, bT, o2, h0);
  }
  k_ln<<<dim3(NTOK), 256, 0, stream>>>(o2, lnw, lnb, outp);
}